// Round 1
// baseline (1259.828 us; speedup 1.0000x reference)
//
#include <hip/hip_runtime.h>
#include <hip/hip_bf16.h>
#include <math.h>

#define N_TOK 22506
#define LEN   11253
#define DMODEL 256

#define BM 64
#define BN 64
#define BK 16

// Generic tiled f32 GEMM: C[M x Nc] = (A (+ A2)) [M x K] @ W [K x Nc] + bias, optional relu.
__global__ __launch_bounds__(256) void gemm_f32(
    const float* __restrict__ A, const float* __restrict__ A2,
    const float* __restrict__ W, const float* __restrict__ bias,
    float* __restrict__ C, int M, int Nc, int K, int relu)
{
    __shared__ float As[BK][BM + 1];
    __shared__ float Bs[BK][BN + 1];
    int tid = threadIdx.x;
    int bm = blockIdx.y * BM, bn = blockIdx.x * BN;
    int tx = tid & 15, ty = tid >> 4;
    float acc[4][4] = {};

    for (int k0 = 0; k0 < K; k0 += BK) {
        // load A tile (BM x BK)
        #pragma unroll
        for (int e = tid; e < BM * BK; e += 256) {
            int r = e / BK, c = e % BK;
            int gr = bm + r;
            float v = 0.f;
            if (gr < M) {
                size_t gi = (size_t)gr * K + k0 + c;
                v = A[gi];
                if (A2) v += A2[gi];
            }
            As[c][r] = v;
        }
        // load W tile (BK x BN)
        #pragma unroll
        for (int e = tid; e < BK * BN; e += 256) {
            int r = e / BN, c = e % BN;
            Bs[r][c] = W[(size_t)(k0 + r) * Nc + bn + c];
        }
        __syncthreads();
        #pragma unroll
        for (int kk = 0; kk < BK; ++kk) {
            float a[4], b[4];
            #pragma unroll
            for (int i = 0; i < 4; ++i) a[i] = As[kk][ty * 4 + i];
            #pragma unroll
            for (int j = 0; j < 4; ++j) b[j] = Bs[kk][tx * 4 + j];
            #pragma unroll
            for (int i = 0; i < 4; ++i)
                #pragma unroll
                for (int j = 0; j < 4; ++j)
                    acc[i][j] += a[i] * b[j];
        }
        __syncthreads();
    }

    #pragma unroll
    for (int i = 0; i < 4; ++i) {
        int gr = bm + ty * 4 + i;
        if (gr >= M) continue;
        #pragma unroll
        for (int j = 0; j < 4; ++j) {
            int gc = bn + tx * 4 + j;
            float v = acc[i][j] + (bias ? bias[gc] : 0.f);
            if (relu) v = fmaxf(v, 0.f);
            C[(size_t)gr * Nc + gc] = v;
        }
    }
}

// In-place softmax over contiguous groups of 16 (attention weights per head).
__global__ __launch_bounds__(256) void softmax16(float* __restrict__ p, int total)
{
    int i = blockIdx.x * blockDim.x + threadIdx.x;
    if (i >= total) return;
    float* q = p + (size_t)i * 16;
    float m = -1e30f;
    #pragma unroll
    for (int j = 0; j < 16; ++j) m = fmaxf(m, q[j]);
    float s = 0.f;
    float e[16];
    #pragma unroll
    for (int j = 0; j < 16; ++j) { e[j] = expf(q[j] - m); s += e[j]; }
    float inv = 1.f / s;
    #pragma unroll
    for (int j = 0; j < 16; ++j) q[j] = e[j] * inv;
}

// Deformable sampling: one block per token; 8 heads x 32 dims = 256 threads.
__global__ __launch_bounds__(256) void ms_sample(
    const float* __restrict__ value, const float* __restrict__ off,
    const float* __restrict__ aw, const float* __restrict__ refp,
    float* __restrict__ out)
{
    const int starts[4] = {0, 8464, 10580, 11109};
    const int sizes[4]  = {92, 46, 23, 12};
    int n = blockIdx.x;
    int b = n / LEN;
    int t = threadIdx.x;

    __shared__ float s_off[256];
    __shared__ float s_aw[128];
    __shared__ float s_ref[8];
    s_off[t] = off[(size_t)n * 256 + t];
    if (t < 128) s_aw[t] = aw[(size_t)n * 128 + t];
    if (t < 8)   s_ref[t] = refp[(size_t)n * 8 + t];
    __syncthreads();

    int h = t >> 5;   // head 0..7
    int d = t & 31;   // dim within head
    float acc = 0.f;

    #pragma unroll
    for (int l = 0; l < 4; ++l) {
        int wl = sizes[l];
        float wf = (float)wl;
        int st = starts[l];
        #pragma unroll
        for (int p = 0; p < 4; ++p) {
            float ox = s_off[h * 32 + l * 8 + p * 2 + 0];
            float oy = s_off[h * 32 + l * 8 + p * 2 + 1];
            float locx = s_ref[l * 2 + 0] + ox / wf;
            float locy = s_ref[l * 2 + 1] + oy / wf;
            float x = locx * wf - 0.5f;
            float y = locy * wf - 0.5f;
            float x0f = floorf(x), y0f = floorf(y);
            float fx = x - x0f, fy = y - y0f;
            int x0 = (int)x0f, y0 = (int)y0f;
            float a = s_aw[h * 16 + l * 4 + p];
            float w00 = (1.f - fx) * (1.f - fy) * a;
            float w10 = fx * (1.f - fy) * a;
            float w01 = (1.f - fx) * fy * a;
            float w11 = fx * fy * a;

            #pragma unroll
            for (int c = 0; c < 4; ++c) {
                int xi = x0 + (c & 1);
                int yi = y0 + (c >> 1);
                float wgt = (c == 0) ? w00 : (c == 1) ? w10 : (c == 2) ? w01 : w11;
                if (xi >= 0 && xi < wl && yi >= 0 && yi < wl) {
                    size_t idx = ((size_t)(b * LEN + st + yi * wl + xi) * 8 + h) * 32 + d;
                    acc += wgt * value[idx];
                }
            }
        }
    }
    out[(size_t)n * 256 + h * 32 + d] = acc;
}

// out = LayerNorm(a + dl) rowwise over 256 columns. out may alias dl.
__global__ __launch_bounds__(256) void add_ln(
    const float* __restrict__ a, const float* __restrict__ dl,
    const float* __restrict__ g, const float* __restrict__ beta,
    float* __restrict__ out)
{
    int n = blockIdx.x, t = threadIdx.x;
    size_t base = (size_t)n * 256;
    float v = a[base + t] + dl[base + t];
    __shared__ float red[256];
    red[t] = v; __syncthreads();
    #pragma unroll
    for (int s = 128; s > 0; s >>= 1) { if (t < s) red[t] += red[t + s]; __syncthreads(); }
    float mean = red[0] * (1.f / 256.f);
    __syncthreads();
    float c = v - mean;
    red[t] = c * c; __syncthreads();
    #pragma unroll
    for (int s = 128; s > 0; s >>= 1) { if (t < s) red[t] += red[t + s]; __syncthreads(); }
    float var = red[0] * (1.f / 256.f);
    float r = rsqrtf(var + 1e-5f);
    out[base + t] = g[t] * c * r + beta[t];
}

extern "C" void kernel_launch(void* const* d_in, const int* in_sizes, int n_in,
                              void* d_out, int out_size, void* d_ws, size_t ws_size,
                              hipStream_t stream) {
    const float* src    = (const float*)d_in[0];
    const float* pos    = (const float*)d_in[1];
    const float* refp   = (const float*)d_in[2];
    const float* w_value= (const float*)d_in[3];
    const float* b_value= (const float*)d_in[4];
    const float* w_off  = (const float*)d_in[5];
    const float* b_off  = (const float*)d_in[6];
    const float* w_attn = (const float*)d_in[7];
    const float* b_attn = (const float*)d_in[8];
    const float* w_out  = (const float*)d_in[9];
    const float* b_out  = (const float*)d_in[10];
    const float* ln1_g  = (const float*)d_in[11];
    const float* ln1_b  = (const float*)d_in[12];
    const float* w1     = (const float*)d_in[13];
    const float* b1     = (const float*)d_in[14];
    const float* w2     = (const float*)d_in[15];
    const float* b2     = (const float*)d_in[16];
    const float* ln2_g  = (const float*)d_in[17];
    const float* ln2_b  = (const float*)d_in[18];
    // d_in[19] = spatial_shapes (int64) — compile-time constants, unused.

    float* ws = (float*)d_ws;
    const size_t NV = (size_t)N_TOK * 256;
    float* X  = ws;            // src2, then x (23 MB)
    float* R  = ws + NV;       // overlay region (92 MB)
    float* V  = R;                               // value
    float* O  = R + NV;                          // offsets
    float* AW = R + 2 * NV;                      // attn logits -> weights
    float* S  = AW + (size_t)N_TOK * 128;        // sampled output
    float* Hb = R;                               // FFN hidden (reuses V..S after they die)
    float* out = (float*)d_out;

    dim3 blk(256);
    auto grid_g = [](int M, int Nc) { return dim3((Nc + BN - 1) / BN, (M + BM - 1) / BM); };

    // 1. value projection (input = src, NOT src+pos)
    gemm_f32<<<grid_g(N_TOK, 256), blk, 0, stream>>>(src, nullptr, w_value, b_value, V, N_TOK, 256, 256, 0);
    // 2. offsets from q = src + pos
    gemm_f32<<<grid_g(N_TOK, 256), blk, 0, stream>>>(src, pos, w_off, b_off, O, N_TOK, 256, 256, 0);
    // 3. attention logits from q
    gemm_f32<<<grid_g(N_TOK, 128), blk, 0, stream>>>(src, pos, w_attn, b_attn, AW, N_TOK, 128, 256, 0);
    // 4. softmax over L*P=16 per (token, head)
    softmax16<<<(N_TOK * 8 + 255) / 256, blk, 0, stream>>>(AW, N_TOK * 8);
    // 5. deformable bilinear sampling
    ms_sample<<<N_TOK, blk, 0, stream>>>(V, O, AW, refp, S);
    // 6. output projection -> src2 (into X)
    gemm_f32<<<grid_g(N_TOK, 256), blk, 0, stream>>>(S, nullptr, w_out, b_out, X, N_TOK, 256, 256, 0);
    // 7. x = LN(src + src2)  (in-place on X)
    add_ln<<<N_TOK, blk, 0, stream>>>(src, X, ln1_g, ln1_b, X);
    // 8. hidden = relu(x @ w1 + b1)
    gemm_f32<<<grid_g(N_TOK, 1024), blk, 0, stream>>>(X, nullptr, w1, b1, Hb, N_TOK, 1024, 256, 1);
    // 9. y = hidden @ w2 + b2 -> d_out
    gemm_f32<<<grid_g(N_TOK, 256), blk, 0, stream>>>(Hb, nullptr, w2, b2, out, N_TOK, 256, 1024, 0);
    // 10. out = LN(x + y)  (in-place on d_out)
    add_ln<<<N_TOK, blk, 0, stream>>>(X, out, ln2_g, ln2_b, out);
}

// Round 2
// 491.909 us; speedup vs baseline: 2.5611x; 2.5611x over previous
//
#include <hip/hip_runtime.h>
#include <hip/hip_bf16.h>
#include <math.h>

#define N_TOK 22506
#define LEN   11253

typedef unsigned short u16;
typedef __attribute__((ext_vector_type(8))) short short8;
typedef __attribute__((ext_vector_type(4))) float f32x4;

static __device__ __forceinline__ u16 f2bf(float f) {
    unsigned int u = __builtin_bit_cast(unsigned int, f);
    u = (u + 0x7fffu + ((u >> 16) & 1u)) >> 16;
    return (u16)u;
}
static __device__ __forceinline__ float bf2f(u16 u) {
    unsigned int x = ((unsigned int)u) << 16;
    return __builtin_bit_cast(float, x);
}

// ---- weight transpose + bf16 convert: Wt[n][k] = bf16(W[k][n]) ----
__global__ __launch_bounds__(256) void wtrans(const float* __restrict__ W,
                                              u16* __restrict__ Wt, int K, int Nc)
{
    int i = blockIdx.x * 256 + threadIdx.x;
    if (i >= K * Nc) return;
    int k = i / Nc, n = i % Nc;
    Wt[(size_t)n * K + k] = f2bf(W[i]);
}

// ---- srcb = bf16(src), qb = bf16(src+pos) ----
__global__ __launch_bounds__(256) void cvt_src(const float* __restrict__ src,
                                               const float* __restrict__ pos,
                                               u16* __restrict__ srcb, u16* __restrict__ qb,
                                               int n4)
{
    int i = blockIdx.x * 256 + threadIdx.x;
    if (i >= n4) return;
    float4 s = ((const float4*)src)[i];
    float4 p = ((const float4*)pos)[i];
    u16 sb[4] = { f2bf(s.x), f2bf(s.y), f2bf(s.z), f2bf(s.w) };
    u16 qb4[4] = { f2bf(s.x + p.x), f2bf(s.y + p.y), f2bf(s.z + p.z), f2bf(s.w + p.w) };
    *(ushort4*)(srcb + (size_t)i * 4) = *(ushort4*)sb;
    *(ushort4*)(qb + (size_t)i * 4) = *(ushort4*)qb4;
}

// ---- bf16 MFMA GEMM: C[M x Nc] = A[M x K](bf16) @ Bt[Nc x K]^T(bf16) + bias ----
// 128x128 tile, BK=64, 4 waves (2x2), each wave 64x64 via 4x4 frags of 16x16x32.
#define BMT 128
#define BNT 128
#define BKT 64

__global__ __launch_bounds__(256) void gemm_mfma(
    const u16* __restrict__ A, const u16* __restrict__ Bt,
    const float* __restrict__ bias, float* __restrict__ Cf, u16* __restrict__ Cb,
    int M, int Nc, int K, int relu)
{
    __shared__ u16 As[BMT * BKT];
    __shared__ u16 Bs[BNT * BKT];
    int tid = threadIdx.x;
    int lane = tid & 63, wid = tid >> 6;
    int wr = wid >> 1, wc = wid & 1;
    int bm = blockIdx.y * BMT, bn = blockIdx.x * BNT;

    f32x4 acc[4][4] = {};

    int sr = tid >> 3;          // 0..31 row base per stage iter
    int ss = tid & 7;           // slot 0..7 (8 bf16 = 16B each)

    for (int k0 = 0; k0 < K; k0 += BKT) {
        #pragma unroll
        for (int i = 0; i < 4; ++i) {
            int r = i * 32 + sr;
            short8 v = {0,0,0,0,0,0,0,0};
            int gr = bm + r;
            if (gr < M) v = *(const short8*)(A + (size_t)gr * K + k0 + ss * 8);
            *(short8*)(&As[r * BKT + ((ss ^ (r & 7)) << 3)]) = v;
        }
        #pragma unroll
        for (int i = 0; i < 4; ++i) {
            int r = i * 32 + sr;
            short8 v = *(const short8*)(Bt + (size_t)(bn + r) * K + k0 + ss * 8);
            *(short8*)(&Bs[r * BKT + ((ss ^ (r & 7)) << 3)]) = v;
        }
        __syncthreads();

        int rlo = lane & 15, khalf = lane >> 4;
        short8 af[4][2], bfr[4][2];
        #pragma unroll
        for (int mi = 0; mi < 4; ++mi) {
            int row = wr * 64 + mi * 16 + rlo;
            #pragma unroll
            for (int kk = 0; kk < 2; ++kk) {
                int slot = khalf + kk * 4;
                af[mi][kk] = *(const short8*)(&As[row * BKT + ((slot ^ (row & 7)) << 3)]);
            }
        }
        #pragma unroll
        for (int ni = 0; ni < 4; ++ni) {
            int col = wc * 64 + ni * 16 + rlo;
            #pragma unroll
            for (int kk = 0; kk < 2; ++kk) {
                int slot = khalf + kk * 4;
                bfr[ni][kk] = *(const short8*)(&Bs[col * BKT + ((slot ^ (col & 7)) << 3)]);
            }
        }
        #pragma unroll
        for (int mi = 0; mi < 4; ++mi)
            #pragma unroll
            for (int ni = 0; ni < 4; ++ni)
                #pragma unroll
                for (int kk = 0; kk < 2; ++kk)
                    acc[mi][ni] = __builtin_amdgcn_mfma_f32_16x16x32_bf16(
                        af[mi][kk], bfr[ni][kk], acc[mi][ni], 0, 0, 0);
        __syncthreads();
    }

    int col_l = lane & 15, rgrp = lane >> 4;
    #pragma unroll
    for (int mi = 0; mi < 4; ++mi) {
        #pragma unroll
        for (int j = 0; j < 4; ++j) {
            int row = bm + wr * 64 + mi * 16 + rgrp * 4 + j;
            if (row >= M) continue;
            #pragma unroll
            for (int ni = 0; ni < 4; ++ni) {
                int col = bn + wc * 64 + ni * 16 + col_l;
                float v = acc[mi][ni][j];
                if (bias) v += bias[col];
                if (relu) v = fmaxf(v, 0.f);
                if (Cf) Cf[(size_t)row * Nc + col] = v;
                if (Cb) Cb[(size_t)row * Nc + col] = f2bf(v);
            }
        }
    }
}

// ---- deformable sampling with fused softmax; bf16 value, bf16 out ----
__global__ __launch_bounds__(256) void ms_sample(
    const u16* __restrict__ value, const float* __restrict__ off,
    const float* __restrict__ logits, const float* __restrict__ refp,
    u16* __restrict__ out)
{
    const int starts[4] = {0, 8464, 10580, 11109};
    const int sizes[4]  = {92, 46, 23, 12};
    int n = blockIdx.x;
    int b = n / LEN;
    int t = threadIdx.x;

    __shared__ float s_off[256];
    __shared__ float s_aw[128];
    __shared__ float s_ref[8];
    s_off[t] = off[(size_t)n * 256 + t];
    if (t < 128) s_aw[t] = logits[(size_t)n * 128 + t];
    if (t < 8)   s_ref[t] = refp[(size_t)n * 8 + t];
    __syncthreads();
    if (t < 8) {
        float* q = s_aw + t * 16;
        float m = -1e30f;
        #pragma unroll
        for (int j = 0; j < 16; ++j) m = fmaxf(m, q[j]);
        float s = 0.f;
        #pragma unroll
        for (int j = 0; j < 16; ++j) { q[j] = expf(q[j] - m); s += q[j]; }
        float inv = 1.f / s;
        #pragma unroll
        for (int j = 0; j < 16; ++j) q[j] *= inv;
    }
    __syncthreads();

    int h = t >> 5;
    int d = t & 31;
    float acc = 0.f;

    #pragma unroll
    for (int l = 0; l < 4; ++l) {
        int wl = sizes[l];
        float wf = (float)wl;
        int st = starts[l];
        #pragma unroll
        for (int p = 0; p < 4; ++p) {
            float ox = s_off[h * 32 + l * 8 + p * 2 + 0];
            float oy = s_off[h * 32 + l * 8 + p * 2 + 1];
            float x = s_ref[l * 2 + 0] * wf + ox - 0.5f;
            float y = s_ref[l * 2 + 1] * wf + oy - 0.5f;
            float x0f = floorf(x), y0f = floorf(y);
            float fx = x - x0f, fy = y - y0f;
            int x0 = (int)x0f, y0 = (int)y0f;
            float a = s_aw[h * 16 + l * 4 + p];
            float w00 = (1.f - fx) * (1.f - fy) * a;
            float w10 = fx * (1.f - fy) * a;
            float w01 = (1.f - fx) * fy * a;
            float w11 = fx * fy * a;
            #pragma unroll
            for (int c = 0; c < 4; ++c) {
                int xi = x0 + (c & 1);
                int yi = y0 + (c >> 1);
                float wgt = (c == 0) ? w00 : (c == 1) ? w10 : (c == 2) ? w01 : w11;
                if (xi >= 0 && xi < wl && yi >= 0 && yi < wl) {
                    size_t idx = ((size_t)(b * LEN + st + yi * wl + xi) * 8 + h) * 32 + d;
                    acc += wgt * bf2f(value[idx]);
                }
            }
        }
    }
    out[(size_t)n * 256 + h * 32 + d] = f2bf(acc);
}

// ---- out = LayerNorm(a + dl); optional bf16 copy ----
__global__ __launch_bounds__(256) void add_ln(
    const float* __restrict__ a, const float* __restrict__ dl,
    const float* __restrict__ g, const float* __restrict__ beta,
    float* __restrict__ outf, u16* __restrict__ outb)
{
    int n = blockIdx.x, t = threadIdx.x;
    size_t base = (size_t)n * 256;
    float v = a[base + t] + dl[base + t];
    __shared__ float red[256];
    red[t] = v; __syncthreads();
    #pragma unroll
    for (int s = 128; s > 0; s >>= 1) { if (t < s) red[t] += red[t + s]; __syncthreads(); }
    float mean = red[0] * (1.f / 256.f);
    __syncthreads();
    float c = v - mean;
    red[t] = c * c; __syncthreads();
    #pragma unroll
    for (int s = 128; s > 0; s >>= 1) { if (t < s) red[t] += red[t + s]; __syncthreads(); }
    float var = red[0] * (1.f / 256.f);
    float r = rsqrtf(var + 1e-5f);
    float o = g[t] * c * r + beta[t];
    outf[base + t] = o;
    if (outb) outb[base + t] = f2bf(o);
}

extern "C" void kernel_launch(void* const* d_in, const int* in_sizes, int n_in,
                              void* d_out, int out_size, void* d_ws, size_t ws_size,
                              hipStream_t stream) {
    const float* src    = (const float*)d_in[0];
    const float* pos    = (const float*)d_in[1];
    const float* refp   = (const float*)d_in[2];
    const float* w_value= (const float*)d_in[3];
    const float* b_value= (const float*)d_in[4];
    const float* w_off  = (const float*)d_in[5];
    const float* b_off  = (const float*)d_in[6];
    const float* w_attn = (const float*)d_in[7];
    const float* b_attn = (const float*)d_in[8];
    const float* w_out  = (const float*)d_in[9];
    const float* b_out  = (const float*)d_in[10];
    const float* ln1_g  = (const float*)d_in[11];
    const float* ln1_b  = (const float*)d_in[12];
    const float* w1     = (const float*)d_in[13];
    const float* b1     = (const float*)d_in[14];
    const float* w2     = (const float*)d_in[15];
    const float* b2     = (const float*)d_in[16];
    const float* ln2_g  = (const float*)d_in[17];
    const float* ln2_b  = (const float*)d_in[18];

    const size_t NV = (size_t)N_TOK * 256;
    char* w = (char*)d_ws;
    float* X   = (float*)w;                    // NV f32
    u16*   Xb  = (u16*)(w + NV * 4);           // NV bf16
    char*  C0  = w + NV * 6;
    u16*   srcb= (u16*)C0;                     // NV bf16 (later S)
    u16*   Sb  = srcb;
    u16*   qb  = (u16*)(C0 + NV * 2);          // NV bf16
    u16*   Vb  = (u16*)(C0 + NV * 4);          // NV bf16
    float* O   = (float*)(C0 + NV * 6);        // NV f32
    float* AW  = (float*)(C0 + NV * 10);       // N_TOK*128 f32
    u16*   Hb  = (u16*)C0;                     // N_TOK*1024 bf16 overlay (8 B/NV <= 10)
    char*  WB  = C0 + NV * 12;
    u16* wv_t   = (u16*)WB;            // 256*256
    u16* wo_t   = wv_t + 65536;        // 256*256
    u16* wa_t   = wo_t + 65536;        // 128*256
    u16* wout_t = wa_t + 32768;        // 256*256
    u16* w1_t   = wout_t + 65536;      // 1024*256
    u16* w2_t   = w1_t + 262144;       // 256*1024
    float* out  = (float*)d_out;

    dim3 blk(256);
    // weight transposes
    wtrans<<<(65536 + 255) / 256, blk, 0, stream>>>(w_value, wv_t, 256, 256);
    wtrans<<<(65536 + 255) / 256, blk, 0, stream>>>(w_off,   wo_t, 256, 256);
    wtrans<<<(32768 + 255) / 256, blk, 0, stream>>>(w_attn,  wa_t, 256, 128);
    wtrans<<<(65536 + 255) / 256, blk, 0, stream>>>(w_out,   wout_t, 256, 256);
    wtrans<<<(262144 + 255) / 256, blk, 0, stream>>>(w1,     w1_t, 256, 1024);
    wtrans<<<(262144 + 255) / 256, blk, 0, stream>>>(w2,     w2_t, 1024, 256);
    // activations -> bf16
    cvt_src<<<((int)(NV / 4) + 255) / 256, blk, 0, stream>>>(src, pos, srcb, qb, (int)(NV / 4));

    int MB = (N_TOK + BMT - 1) / BMT;  // 176
    // 1. value = src @ w_value (+b) -> bf16
    gemm_mfma<<<dim3(2, MB), blk, 0, stream>>>(srcb, wv_t, b_value, nullptr, Vb, N_TOK, 256, 256, 0);
    // 2. offsets = q @ w_off (+b) -> f32
    gemm_mfma<<<dim3(2, MB), blk, 0, stream>>>(qb, wo_t, b_off, O, nullptr, N_TOK, 256, 256, 0);
    // 3. attn logits = q @ w_attn (+b) -> f32
    gemm_mfma<<<dim3(1, MB), blk, 0, stream>>>(qb, wa_t, b_attn, AW, nullptr, N_TOK, 128, 256, 0);
    // 4. sampling (fused softmax) -> Sb bf16
    ms_sample<<<dim3(N_TOK), blk, 0, stream>>>(Vb, O, AW, refp, Sb);
    // 5. src2 = S @ w_out (+b) -> X f32
    gemm_mfma<<<dim3(2, MB), blk, 0, stream>>>(Sb, wout_t, b_out, X, nullptr, N_TOK, 256, 256, 0);
    // 6. x = LN(src + src2) -> X f32 + Xb bf16
    add_ln<<<dim3(N_TOK), blk, 0, stream>>>(src, X, ln1_g, ln1_b, X, Xb);
    // 7. hidden = relu(x @ w1 + b1) -> Hb bf16
    gemm_mfma<<<dim3(8, MB), blk, 0, stream>>>(Xb, w1_t, b1, nullptr, Hb, N_TOK, 1024, 256, 1);
    // 8. y = hidden @ w2 + b2 -> out f32
    gemm_mfma<<<dim3(2, MB), blk, 0, stream>>>(Hb, w2_t, b2, out, nullptr, N_TOK, 256, 1024, 0);
    // 9. out = LN(x + y)
    add_ln<<<dim3(N_TOK), blk, 0, stream>>>(X, out, ln2_g, ln2_b, out, nullptr);
}

// Round 3
// 321.118 us; speedup vs baseline: 3.9233x; 1.5319x over previous
//
#include <hip/hip_runtime.h>
#include <hip/hip_bf16.h>
#include <math.h>

#define N_TOK 22506
#define LEN   11253

typedef unsigned short u16;
typedef __attribute__((ext_vector_type(8))) short short8;
typedef __attribute__((ext_vector_type(4))) float f32x4;

static __device__ __forceinline__ u16 f2bf(float f) {
    unsigned int u = __builtin_bit_cast(unsigned int, f);
    u = (u + 0x7fffu + ((u >> 16) & 1u)) >> 16;
    return (u16)u;
}
static __device__ __forceinline__ float bf2f(u16 u) {
    unsigned int x = ((unsigned int)u) << 16;
    return __builtin_bit_cast(float, x);
}

// ---- weight transpose + bf16 convert: Wt[n][k] = bf16(W[k][n]) ----
__global__ __launch_bounds__(256) void wtrans(const float* __restrict__ W,
                                              u16* __restrict__ Wt, int K, int Nc)
{
    int i = blockIdx.x * 256 + threadIdx.x;
    if (i >= K * Nc) return;
    int k = i / Nc, n = i % Nc;
    Wt[(size_t)n * K + k] = f2bf(W[i]);
}

__global__ __launch_bounds__(256) void bias_cat(const float* __restrict__ b0,
                                                const float* __restrict__ b1,
                                                float* __restrict__ o)
{
    int i = blockIdx.x * 256 + threadIdx.x;
    if (i < 256) o[i] = b0[i];
    else if (i < 384) o[i] = b1[i - 256];
}

// ---- srcb = bf16(src), qb = bf16(src+pos) ----
__global__ __launch_bounds__(256) void cvt_src(const float* __restrict__ src,
                                               const float* __restrict__ pos,
                                               u16* __restrict__ srcb, u16* __restrict__ qb,
                                               int n4)
{
    int i = blockIdx.x * 256 + threadIdx.x;
    if (i >= n4) return;
    float4 s = ((const float4*)src)[i];
    float4 p = ((const float4*)pos)[i];
    u16 sb[4] = { f2bf(s.x), f2bf(s.y), f2bf(s.z), f2bf(s.w) };
    u16 qb4[4] = { f2bf(s.x + p.x), f2bf(s.y + p.y), f2bf(s.z + p.z), f2bf(s.w + p.w) };
    *(ushort4*)(srcb + (size_t)i * 4) = *(ushort4*)sb;
    *(ushort4*)(qb + (size_t)i * 4) = *(ushort4*)qb4;
}

// ---- bf16 MFMA GEMM: C[M x Nc] = A[M x K](bf16) @ Bt[Nc x K]^T(bf16) + bias ----
#define BMT 128
#define BNT 128
#define BKT 64

__global__ __launch_bounds__(256) void gemm_mfma(
    const u16* __restrict__ A, const u16* __restrict__ Bt,
    const float* __restrict__ bias, float* __restrict__ Cf, u16* __restrict__ Cb,
    int M, int Nc, int K, int relu)
{
    __shared__ u16 As[BMT * BKT];
    __shared__ u16 Bs[BNT * BKT];
    int tid = threadIdx.x;
    int lane = tid & 63, wid = tid >> 6;
    int wr = wid >> 1, wc = wid & 1;
    int bm = blockIdx.y * BMT, bn = blockIdx.x * BNT;

    f32x4 acc[4][4] = {};

    int sr = tid >> 3;
    int ss = tid & 7;

    for (int k0 = 0; k0 < K; k0 += BKT) {
        #pragma unroll
        for (int i = 0; i < 4; ++i) {
            int r = i * 32 + sr;
            short8 v = {0,0,0,0,0,0,0,0};
            int gr = bm + r;
            if (gr < M) v = *(const short8*)(A + (size_t)gr * K + k0 + ss * 8);
            *(short8*)(&As[r * BKT + ((ss ^ (r & 7)) << 3)]) = v;
        }
        #pragma unroll
        for (int i = 0; i < 4; ++i) {
            int r = i * 32 + sr;
            short8 v = *(const short8*)(Bt + (size_t)(bn + r) * K + k0 + ss * 8);
            *(short8*)(&Bs[r * BKT + ((ss ^ (r & 7)) << 3)]) = v;
        }
        __syncthreads();

        int rlo = lane & 15, khalf = lane >> 4;
        short8 af[4][2], bfr[4][2];
        #pragma unroll
        for (int mi = 0; mi < 4; ++mi) {
            int row = wr * 64 + mi * 16 + rlo;
            #pragma unroll
            for (int kk = 0; kk < 2; ++kk) {
                int slot = khalf + kk * 4;
                af[mi][kk] = *(const short8*)(&As[row * BKT + ((slot ^ (row & 7)) << 3)]);
            }
        }
        #pragma unroll
        for (int ni = 0; ni < 4; ++ni) {
            int col = wc * 64 + ni * 16 + rlo;
            #pragma unroll
            for (int kk = 0; kk < 2; ++kk) {
                int slot = khalf + kk * 4;
                bfr[ni][kk] = *(const short8*)(&Bs[col * BKT + ((slot ^ (col & 7)) << 3)]);
            }
        }
        #pragma unroll
        for (int mi = 0; mi < 4; ++mi)
            #pragma unroll
            for (int ni = 0; ni < 4; ++ni)
                #pragma unroll
                for (int kk = 0; kk < 2; ++kk)
                    acc[mi][ni] = __builtin_amdgcn_mfma_f32_16x16x32_bf16(
                        af[mi][kk], bfr[ni][kk], acc[mi][ni], 0, 0, 0);
        __syncthreads();
    }

    int col_l = lane & 15, rgrp = lane >> 4;
    #pragma unroll
    for (int mi = 0; mi < 4; ++mi) {
        #pragma unroll
        for (int j = 0; j < 4; ++j) {
            int row = bm + wr * 64 + mi * 16 + rgrp * 4 + j;
            if (row >= M) continue;
            #pragma unroll
            for (int ni = 0; ni < 4; ++ni) {
                int col = bn + wc * 64 + ni * 16 + col_l;
                float v = acc[mi][ni][j];
                if (bias) v += bias[col];
                if (relu) v = fmaxf(v, 0.f);
                if (Cf) Cf[(size_t)row * Nc + col] = v;
                if (Cb) Cb[(size_t)row * Nc + col] = f2bf(v);
            }
        }
    }
}

// ---- deformable sampling, fused softmax. 1 wave per token, 4 tokens/block.
// lane = h*8 + dq; each lane owns dims [dq*4, dq*4+4) of head h. ----
__global__ __launch_bounds__(256) void ms_sample(
    const u16* __restrict__ value, const float* __restrict__ oa,
    const float* __restrict__ refp, u16* __restrict__ out)
{
    const int starts[4] = {0, 8464, 10580, 11109};
    const int sizes[4]  = {92, 46, 23, 12};
    int t = threadIdx.x;
    int wv = t >> 6, lane = t & 63;
    int n = blockIdx.x * 4 + wv;
    bool valid = n < N_TOK;

    __shared__ float s_off[4][264];  // stride-33 padded per head
    __shared__ float s_aw[4][136];   // stride-17 padded per head
    __shared__ float s_ref[4][8];

    if (valid) {
        float4 o4 = *(const float4*)(oa + (size_t)n * 384 + lane * 4);
        int v0 = lane * 4;
        s_off[wv][v0     + (v0 >> 5)]       = o4.x;
        s_off[wv][v0 + 1 + ((v0 + 1) >> 5)] = o4.y;
        s_off[wv][v0 + 2 + ((v0 + 2) >> 5)] = o4.z;
        s_off[wv][v0 + 3 + ((v0 + 3) >> 5)] = o4.w;
        if (lane < 32) {
            float4 a4 = *(const float4*)(oa + (size_t)n * 384 + 256 + lane * 4);
            int u0 = lane * 4, pu = u0 + (u0 >> 4);
            s_aw[wv][pu]     = a4.x;
            s_aw[wv][pu + 1] = a4.y;
            s_aw[wv][pu + 2] = a4.z;
            s_aw[wv][pu + 3] = a4.w;
        }
        if (lane < 2) {
            *(float4*)(&s_ref[wv][lane * 4]) = *(const float4*)(refp + (size_t)n * 8 + lane * 4);
        }
    }
    __syncthreads();
    if (valid && lane < 8) {
        float* q = &s_aw[wv][lane * 17];
        float m = -1e30f;
        #pragma unroll
        for (int j = 0; j < 16; ++j) m = fmaxf(m, q[j]);
        float s = 0.f;
        #pragma unroll
        for (int j = 0; j < 16; ++j) { q[j] = expf(q[j] - m); s += q[j]; }
        float inv = 1.f / s;
        #pragma unroll
        for (int j = 0; j < 16; ++j) q[j] *= inv;
    }
    __syncthreads();

    if (!valid) return;

    int h = lane >> 3, dq = lane & 7;
    int hd = h * 32 + dq * 4;
    const float* offh = &s_off[wv][h * 33];
    const float* awh  = &s_aw[wv][h * 17];
    unsigned int tokbase = (n >= LEN) ? (unsigned)LEN : 0u;
    float acc0 = 0.f, acc1 = 0.f, acc2 = 0.f, acc3 = 0.f;

    #pragma unroll
    for (int l = 0; l < 4; ++l) {
        int wl = sizes[l];
        float wf = (float)wl;
        int st = starts[l];
        float rx = s_ref[wv][l * 2]     * wf - 0.5f;
        float ry = s_ref[wv][l * 2 + 1] * wf - 0.5f;
        unsigned int lvlbase = (tokbase + (unsigned)st) * 256u + (unsigned)hd;
        #pragma unroll
        for (int p = 0; p < 4; ++p) {
            float x = rx + offh[l * 8 + p * 2];
            float y = ry + offh[l * 8 + p * 2 + 1];
            float x0f = floorf(x), y0f = floorf(y);
            float fx = x - x0f, fy = y - y0f;
            int x0 = (int)x0f, y0 = (int)y0f;
            float a = awh[l * 4 + p];
            float gx = 1.f - fx, gy = 1.f - fy;
            float w00 = gx * gy * a, w10 = fx * gy * a;
            float w01 = gx * fy * a, w11 = fx * fy * a;
            #pragma unroll
            for (int c = 0; c < 4; ++c) {
                int xi = x0 + (c & 1);
                int yi = y0 + (c >> 1);
                float wgt = (c == 0) ? w00 : (c == 1) ? w10 : (c == 2) ? w01 : w11;
                if ((unsigned)xi < (unsigned)wl && (unsigned)yi < (unsigned)wl) {
                    unsigned int idx = lvlbase + (unsigned)(yi * wl + xi) * 256u;
                    ushort4 v = *(const ushort4*)(value + idx);
                    acc0 += wgt * bf2f(v.x);
                    acc1 += wgt * bf2f(v.y);
                    acc2 += wgt * bf2f(v.z);
                    acc3 += wgt * bf2f(v.w);
                }
            }
        }
    }
    u16 o[4] = { f2bf(acc0), f2bf(acc1), f2bf(acc2), f2bf(acc3) };
    *(ushort4*)(out + (size_t)n * 256 + hd) = *(ushort4*)o;
}

// ---- out = LayerNorm(a + dl); optional bf16 copy ----
__global__ __launch_bounds__(256) void add_ln(
    const float* __restrict__ a, const float* __restrict__ dl,
    const float* __restrict__ g, const float* __restrict__ beta,
    float* __restrict__ outf, u16* __restrict__ outb)
{
    int n = blockIdx.x, t = threadIdx.x;
    size_t base = (size_t)n * 256;
    float v = a[base + t] + dl[base + t];
    __shared__ float red[256];
    red[t] = v; __syncthreads();
    #pragma unroll
    for (int s = 128; s > 0; s >>= 1) { if (t < s) red[t] += red[t + s]; __syncthreads(); }
    float mean = red[0] * (1.f / 256.f);
    __syncthreads();
    float c = v - mean;
    red[t] = c * c; __syncthreads();
    #pragma unroll
    for (int s = 128; s > 0; s >>= 1) { if (t < s) red[t] += red[t + s]; __syncthreads(); }
    float var = red[0] * (1.f / 256.f);
    float r = rsqrtf(var + 1e-5f);
    float o = g[t] * c * r + beta[t];
    outf[base + t] = o;
    if (outb) outb[base + t] = f2bf(o);
}

extern "C" void kernel_launch(void* const* d_in, const int* in_sizes, int n_in,
                              void* d_out, int out_size, void* d_ws, size_t ws_size,
                              hipStream_t stream) {
    const float* src    = (const float*)d_in[0];
    const float* pos    = (const float*)d_in[1];
    const float* refp   = (const float*)d_in[2];
    const float* w_value= (const float*)d_in[3];
    const float* b_value= (const float*)d_in[4];
    const float* w_off  = (const float*)d_in[5];
    const float* b_off  = (const float*)d_in[6];
    const float* w_attn = (const float*)d_in[7];
    const float* b_attn = (const float*)d_in[8];
    const float* w_out  = (const float*)d_in[9];
    const float* b_out  = (const float*)d_in[10];
    const float* ln1_g  = (const float*)d_in[11];
    const float* ln1_b  = (const float*)d_in[12];
    const float* w1     = (const float*)d_in[13];
    const float* b1     = (const float*)d_in[14];
    const float* w2     = (const float*)d_in[15];
    const float* b2     = (const float*)d_in[16];
    const float* ln2_g  = (const float*)d_in[17];
    const float* ln2_b  = (const float*)d_in[18];

    const size_t NV = (size_t)N_TOK * 256;
    char* w = (char*)d_ws;
    float* X   = (float*)w;                    // NV f32
    u16*   Xb  = (u16*)(w + NV * 4);           // NV bf16
    char*  C0  = w + NV * 6;
    u16*   srcb= (u16*)C0;                     // NV bf16 (later S)
    u16*   Sb  = srcb;
    u16*   qb  = (u16*)(C0 + NV * 2);          // NV bf16
    u16*   Vb  = (u16*)(C0 + NV * 4);          // NV bf16
    float* OA  = (float*)(C0 + NV * 6);        // N_TOK*384 f32 = NV*6 bytes
    u16*   Hb  = (u16*)C0;                     // N_TOK*1024 bf16 overlay
    char*  WB  = C0 + NV * 12;
    u16* wv_t   = (u16*)WB;            // 256*256
    u16* woa_t  = wv_t + 65536;        // 384*256 (w_off rows 0..255, w_attn rows 256..383)
    u16* wout_t = woa_t + 98304;       // 256*256
    u16* w1_t   = wout_t + 65536;      // 1024*256
    u16* w2_t   = w1_t + 262144;       // 256*1024
    float* boa  = (float*)(w2_t + 262144); // 384 f32
    float* out  = (float*)d_out;

    dim3 blk(256);
    wtrans<<<(65536 + 255) / 256, blk, 0, stream>>>(w_value, wv_t, 256, 256);
    wtrans<<<(65536 + 255) / 256, blk, 0, stream>>>(w_off,   woa_t, 256, 256);
    wtrans<<<(32768 + 255) / 256, blk, 0, stream>>>(w_attn,  woa_t + 65536, 256, 128);
    wtrans<<<(65536 + 255) / 256, blk, 0, stream>>>(w_out,   wout_t, 256, 256);
    wtrans<<<(262144 + 255) / 256, blk, 0, stream>>>(w1,     w1_t, 256, 1024);
    wtrans<<<(262144 + 255) / 256, blk, 0, stream>>>(w2,     w2_t, 1024, 256);
    bias_cat<<<dim3(2), blk, 0, stream>>>(b_off, b_attn, boa);
    cvt_src<<<((int)(NV / 4) + 255) / 256, blk, 0, stream>>>(src, pos, srcb, qb, (int)(NV / 4));

    int MB = (N_TOK + BMT - 1) / BMT;  // 176
    // value = src @ w_value -> bf16
    gemm_mfma<<<dim3(2, MB), blk, 0, stream>>>(srcb, wv_t, b_value, nullptr, Vb, N_TOK, 256, 256, 0);
    // [off | attn] = q @ [w_off | w_attn] -> f32
    gemm_mfma<<<dim3(3, MB), blk, 0, stream>>>(qb, woa_t, boa, OA, nullptr, N_TOK, 384, 256, 0);
    // sampling (fused softmax) -> Sb bf16
    ms_sample<<<dim3((N_TOK + 3) / 4), blk, 0, stream>>>(Vb, OA, refp, Sb);
    // src2 = S @ w_out -> X f32
    gemm_mfma<<<dim3(2, MB), blk, 0, stream>>>(Sb, wout_t, b_out, X, nullptr, N_TOK, 256, 256, 0);
    // x = LN(src + src2) -> X f32 + Xb bf16
    add_ln<<<dim3(N_TOK), blk, 0, stream>>>(src, X, ln1_g, ln1_b, X, Xb);
    // hidden = relu(x @ w1 + b1) -> Hb bf16
    gemm_mfma<<<dim3(8, MB), blk, 0, stream>>>(Xb, w1_t, b1, nullptr, Hb, N_TOK, 1024, 256, 1);
    // y = hidden @ w2 + b2 -> out f32
    gemm_mfma<<<dim3(2, MB), blk, 0, stream>>>(Hb, w2_t, b2, out, N_TOK ? nullptr : nullptr, N_TOK, 256, 1024, 0);
    // out = LN(x + y)
    add_ln<<<dim3(N_TOK), blk, 0, stream>>>(X, out, ln2_g, ln2_b, out, nullptr);
}

// Round 4
// 243.336 us; speedup vs baseline: 5.1773x; 1.3196x over previous
//
#include <hip/hip_runtime.h>
#include <hip/hip_bf16.h>
#include <math.h>

#define N_TOK 22506
#define LEN   11253
#define BKT 64

typedef unsigned short u16;
typedef __attribute__((ext_vector_type(8))) short short8;
typedef __attribute__((ext_vector_type(4))) float f32x4;

static __device__ __forceinline__ u16 f2bf(float f) {
    unsigned int u = __builtin_bit_cast(unsigned int, f);
    u = (u + 0x7fffu + ((u >> 16) & 1u)) >> 16;
    return (u16)u;
}

// ---- all weight transposes (f32 -> bf16, [K][N] -> [N][K]) + bias concat in one kernel ----
__global__ __launch_bounds__(256) void wprep(
    const float* __restrict__ w_value, const float* __restrict__ w_off,
    const float* __restrict__ w_attn, const float* __restrict__ w_out,
    const float* __restrict__ w1, const float* __restrict__ w2,
    const float* __restrict__ b_off, const float* __restrict__ b_attn,
    u16* __restrict__ wv_t, u16* __restrict__ woa_t, u16* __restrict__ wout_t,
    u16* __restrict__ w1_t, u16* __restrict__ w2_t, float* __restrict__ boa)
{
    int i = blockIdx.x * 256 + threadIdx.x;
    if (i < 65536) {                       // w_value 256x256
        wv_t[(i & 255) * 256 + (i >> 8)] = f2bf(w_value[i]);
    } else if (i < 131072) {               // w_off 256x256 -> woa rows 0..255
        int j = i - 65536;
        woa_t[(j & 255) * 256 + (j >> 8)] = f2bf(w_off[j]);
    } else if (i < 163840) {               // w_attn 256x128 -> woa rows 256..383
        int j = i - 131072;
        woa_t[65536 + (j & 127) * 256 + (j >> 7)] = f2bf(w_attn[j]);
    } else if (i < 229376) {               // w_out 256x256
        int j = i - 163840;
        wout_t[(j & 255) * 256 + (j >> 8)] = f2bf(w_out[j]);
    } else if (i < 491520) {               // w1 256x1024
        int j = i - 229376;
        w1_t[(j & 1023) * 256 + (j >> 10)] = f2bf(w1[j]);
    } else if (i < 753664) {               // w2 1024x256
        int j = i - 491520;
        w2_t[(j & 255) * 1024 + (j >> 8)] = f2bf(w2[j]);
    } else if (i < 754048) {               // bias concat [b_off | b_attn]
        int j = i - 753664;
        boa[j] = (j < 256) ? b_off[j] : b_attn[j - 256];
    }
}

// ---- srcb = bf16(src), qb = bf16(src+pos) ----
__global__ __launch_bounds__(256) void cvt_src(const float* __restrict__ src,
                                               const float* __restrict__ pos,
                                               u16* __restrict__ srcb, u16* __restrict__ qb,
                                               int n4)
{
    int i = blockIdx.x * 256 + threadIdx.x;
    if (i >= n4) return;
    float4 s = ((const float4*)src)[i];
    float4 p = ((const float4*)pos)[i];
    u16 sb[4] = { f2bf(s.x), f2bf(s.y), f2bf(s.z), f2bf(s.w) };
    u16 qb4[4] = { f2bf(s.x + p.x), f2bf(s.y + p.y), f2bf(s.z + p.z), f2bf(s.w + p.w) };
    *(ushort4*)(srcb + (size_t)i * 4) = *(ushort4*)sb;
    *(ushort4*)(qb + (size_t)i * 4) = *(ushort4*)qb4;
}

// ---- bf16 MFMA GEMM (128x128 tile): C = A @ Bt^T + bias, f32 and/or bf16 out ----
#define BMT 128
#define BNT 128

__global__ __launch_bounds__(256) void gemm_mfma(
    const u16* __restrict__ A, const u16* __restrict__ Bt,
    const float* __restrict__ bias, float* __restrict__ Cf, u16* __restrict__ Cb,
    int M, int Nc, int K, int relu)
{
    __shared__ u16 As[BMT * BKT];
    __shared__ u16 Bs[BNT * BKT];
    int tid = threadIdx.x;
    int lane = tid & 63, wid = tid >> 6;
    int wr = wid >> 1, wc = wid & 1;
    int bm = blockIdx.y * BMT, bn = blockIdx.x * BNT;

    f32x4 acc[4][4] = {};
    int sr = tid >> 3, ss = tid & 7;

    for (int k0 = 0; k0 < K; k0 += BKT) {
        #pragma unroll
        for (int i = 0; i < 4; ++i) {
            int r = i * 32 + sr;
            short8 v = {0,0,0,0,0,0,0,0};
            int gr = bm + r;
            if (gr < M) v = *(const short8*)(A + (size_t)gr * K + k0 + ss * 8);
            *(short8*)(&As[r * BKT + ((ss ^ (r & 7)) << 3)]) = v;
        }
        #pragma unroll
        for (int i = 0; i < 4; ++i) {
            int r = i * 32 + sr;
            short8 v = *(const short8*)(Bt + (size_t)(bn + r) * K + k0 + ss * 8);
            *(short8*)(&Bs[r * BKT + ((ss ^ (r & 7)) << 3)]) = v;
        }
        __syncthreads();

        int rlo = lane & 15, khalf = lane >> 4;
        short8 af[4][2], bfr[4][2];
        #pragma unroll
        for (int mi = 0; mi < 4; ++mi) {
            int row = wr * 64 + mi * 16 + rlo;
            #pragma unroll
            for (int kk = 0; kk < 2; ++kk) {
                int slot = khalf + kk * 4;
                af[mi][kk] = *(const short8*)(&As[row * BKT + ((slot ^ (row & 7)) << 3)]);
            }
        }
        #pragma unroll
        for (int ni = 0; ni < 4; ++ni) {
            int col = wc * 64 + ni * 16 + rlo;
            #pragma unroll
            for (int kk = 0; kk < 2; ++kk) {
                int slot = khalf + kk * 4;
                bfr[ni][kk] = *(const short8*)(&Bs[col * BKT + ((slot ^ (col & 7)) << 3)]);
            }
        }
        #pragma unroll
        for (int mi = 0; mi < 4; ++mi)
            #pragma unroll
            for (int ni = 0; ni < 4; ++ni)
                #pragma unroll
                for (int kk = 0; kk < 2; ++kk)
                    acc[mi][ni] = __builtin_amdgcn_mfma_f32_16x16x32_bf16(
                        af[mi][kk], bfr[ni][kk], acc[mi][ni], 0, 0, 0);
        __syncthreads();
    }

    int col_l = lane & 15, rgrp = lane >> 4;
    #pragma unroll
    for (int mi = 0; mi < 4; ++mi) {
        #pragma unroll
        for (int j = 0; j < 4; ++j) {
            int row = bm + wr * 64 + mi * 16 + rgrp * 4 + j;
            if (row >= M) continue;
            #pragma unroll
            for (int ni = 0; ni < 4; ++ni) {
                int col = bn + wc * 64 + ni * 16 + col_l;
                float v = acc[mi][ni][j];
                if (bias) v += bias[col];
                if (relu) v = fmaxf(v, 0.f);
                if (Cf) Cf[(size_t)row * Nc + col] = v;
                if (Cb) Cb[(size_t)row * Nc + col] = f2bf(v);
            }
        }
    }
}

// ---- bf16 MFMA GEMM, Nc=256 fixed, fused residual-add + LayerNorm epilogue ----
// 64-row tile x full 256 cols, 256 threads (4 waves along cols).
__global__ __launch_bounds__(256) void gemm_ln(
    const u16* __restrict__ A, const u16* __restrict__ Bt,
    const float* __restrict__ bias, const float* __restrict__ res,
    const float* __restrict__ g, const float* __restrict__ beta,
    float* __restrict__ outf, u16* __restrict__ outb,
    int M, int K)
{
    __shared__ u16 As[64 * BKT];      // 8 KB
    __shared__ u16 Bs[256 * BKT];     // 32 KB
    int tid = threadIdx.x;
    int lane = tid & 63, wc = tid >> 6;
    int bm = blockIdx.x * 64;
    f32x4 acc[4][4] = {};
    int sr = tid >> 3, ss = tid & 7;

    for (int k0 = 0; k0 < K; k0 += BKT) {
        #pragma unroll
        for (int i = 0; i < 2; ++i) {
            int r = i * 32 + sr;
            short8 v = {0,0,0,0,0,0,0,0};
            int gr = bm + r;
            if (gr < M) v = *(const short8*)(A + (size_t)gr * K + k0 + ss * 8);
            *(short8*)(&As[r * BKT + ((ss ^ (r & 7)) << 3)]) = v;
        }
        #pragma unroll
        for (int i = 0; i < 8; ++i) {
            int r = i * 32 + sr;
            short8 v = *(const short8*)(Bt + (size_t)r * K + k0 + ss * 8);
            *(short8*)(&Bs[r * BKT + ((ss ^ (r & 7)) << 3)]) = v;
        }
        __syncthreads();

        int rlo = lane & 15, khalf = lane >> 4;
        short8 af[4][2], bfr[4][2];
        #pragma unroll
        for (int mi = 0; mi < 4; ++mi) {
            int row = mi * 16 + rlo;
            #pragma unroll
            for (int kk = 0; kk < 2; ++kk) {
                int slot = khalf + kk * 4;
                af[mi][kk] = *(const short8*)(&As[row * BKT + ((slot ^ (row & 7)) << 3)]);
            }
        }
        #pragma unroll
        for (int ni = 0; ni < 4; ++ni) {
            int col = wc * 64 + ni * 16 + rlo;
            #pragma unroll
            for (int kk = 0; kk < 2; ++kk) {
                int slot = khalf + kk * 4;
                bfr[ni][kk] = *(const short8*)(&Bs[col * BKT + ((slot ^ (col & 7)) << 3)]);
            }
        }
        #pragma unroll
        for (int mi = 0; mi < 4; ++mi)
            #pragma unroll
            for (int ni = 0; ni < 4; ++ni)
                #pragma unroll
                for (int kk = 0; kk < 2; ++kk)
                    acc[mi][ni] = __builtin_amdgcn_mfma_f32_16x16x32_bf16(
                        af[mi][kk], bfr[ni][kk], acc[mi][ni], 0, 0, 0);
        __syncthreads();
    }

    // epilogue: v = acc + bias + res; LayerNorm over the 256-col row
    float* red = (float*)As;   // reuse As LDS: s[256], s2[256], mean[64], rstd[64]
    int col_l = lane & 15, rgrp = lane >> 4;
    int colc[4]; float bias_c[4], g_c[4], be_c[4];
    #pragma unroll
    for (int ni = 0; ni < 4; ++ni) {
        colc[ni] = wc * 64 + ni * 16 + col_l;
        bias_c[ni] = bias[colc[ni]];
        g_c[ni]  = g[colc[ni]];
        be_c[ni] = beta[colc[ni]];
    }
    #pragma unroll
    for (int mi = 0; mi < 4; ++mi) {
        #pragma unroll
        for (int j = 0; j < 4; ++j) {
            int rl = mi * 16 + rgrp * 4 + j;
            int row = bm + rl;
            float s = 0.f, s2 = 0.f;
            if (row < M) {
                #pragma unroll
                for (int ni = 0; ni < 4; ++ni) {
                    float v = acc[mi][ni][j] + bias_c[ni] + res[(size_t)row * 256 + colc[ni]];
                    acc[mi][ni][j] = v;
                    s += v; s2 += v * v;
                }
            }
            #pragma unroll
            for (int d = 1; d < 16; d <<= 1) { s += __shfl_xor(s, d); s2 += __shfl_xor(s2, d); }
            if (col_l == 0) { red[wc * 64 + rl] = s; red[256 + wc * 64 + rl] = s2; }
        }
    }
    __syncthreads();
    if (tid < 64) {
        float s  = red[tid] + red[64 + tid] + red[128 + tid] + red[192 + tid];
        float s2 = red[256 + tid] + red[320 + tid] + red[384 + tid] + red[448 + tid];
        float mean = s * (1.f / 256.f);
        float var = s2 * (1.f / 256.f) - mean * mean;
        red[512 + tid] = mean;
        red[576 + tid] = rsqrtf(var + 1e-5f);
    }
    __syncthreads();
    #pragma unroll
    for (int mi = 0; mi < 4; ++mi) {
        #pragma unroll
        for (int j = 0; j < 4; ++j) {
            int rl = mi * 16 + rgrp * 4 + j;
            int row = bm + rl;
            if (row >= M) continue;
            float mean = red[512 + rl], rs = red[576 + rl];
            #pragma unroll
            for (int ni = 0; ni < 4; ++ni) {
                float o = g_c[ni] * (acc[mi][ni][j] - mean) * rs + be_c[ni];
                outf[(size_t)row * 256 + colc[ni]] = o;
                if (outb) outb[(size_t)row * 256 + colc[ni]] = f2bf(o);
            }
        }
    }
}

// ---- deformable sampling, phase-split. 1 wave/token, 4 tokens/block.
// Phase 1: 64 lanes compute 128 (h,pt) pairs (2 each): softmax weight (wave-
// parallel shfl), bilinear weights (x aw x inbounds) + 4 clamped addresses -> LDS.
// Phase 2: lane = h*8+dq owns 4 dims; 16 pts x {2 ds_read_b128, 4 gathers, 16 fma}.
__global__ __launch_bounds__(256) void ms_sample(
    const float* __restrict__ value, const float* __restrict__ oa,
    const float* __restrict__ refp, u16* __restrict__ out)
{
    const int starts[4] = {0, 8464, 10580, 11109};
    const int sizes[4]  = {92, 46, 23, 12};
    int t = threadIdx.x;
    int wv = t >> 6, lane = t & 63;
    int n = blockIdx.x * 4 + wv;

    __shared__ unsigned int s_pd[4][1024];  // per wave: slot (pt*8+h) * 8 dwords

    if (n < N_TOK) {
        const float* oan = oa + (size_t)n * 384;
        unsigned int tokbase = (n >= LEN) ? (unsigned)LEN : 0u;
        #pragma unroll
        for (int rep = 0; rep < 2; ++rep) {
            int q = rep * 64 + lane;          // q = h*16 + pt
            int h = q >> 4, pt = q & 15, l = pt >> 2;
            // softmax over the 16 points of head h (16-lane groups)
            float logit = oan[256 + q];
            float m = logit;
            #pragma unroll
            for (int d = 1; d < 16; d <<= 1) m = fmaxf(m, __shfl_xor(m, d));
            float e = expf(logit - m);
            float ssum = e;
            #pragma unroll
            for (int d = 1; d < 16; d <<= 1) ssum += __shfl_xor(ssum, d);
            float aw = e / ssum;
            // sample position
            float2 off2 = *(const float2*)(oan + 2 * q);
            float2 ref2 = *(const float2*)(refp + (size_t)n * 8 + l * 2);
            int wl = sizes[l];
            float wf = (float)wl;
            float x = ref2.x * wf - 0.5f + off2.x;
            float y = ref2.y * wf - 0.5f + off2.y;
            float x0f = floorf(x), y0f = floorf(y);
            float fx = x - x0f, fy = y - y0f;
            int x0 = (int)x0f, y0 = (int)y0f;
            int x1 = x0 + 1, y1 = y0 + 1;
            float gx = 1.f - fx, gy = 1.f - fy;
            bool bx0 = (unsigned)x0 < (unsigned)wl, bx1 = (unsigned)x1 < (unsigned)wl;
            bool by0 = (unsigned)y0 < (unsigned)wl, by1 = (unsigned)y1 < (unsigned)wl;
            float w00 = (bx0 && by0) ? gx * gy * aw : 0.f;
            float w10 = (bx1 && by0) ? fx * gy * aw : 0.f;
            float w01 = (bx0 && by1) ? gx * fy * aw : 0.f;
            float w11 = (bx1 && by1) ? fx * fy * aw : 0.f;
            int x0c = min(max(x0, 0), wl - 1), x1c = min(max(x1, 0), wl - 1);
            int y0c = min(max(y0, 0), wl - 1), y1c = min(max(y1, 0), wl - 1);
            unsigned int base = (tokbase + (unsigned)starts[l]) * 256u + (unsigned)(h * 32);
            unsigned int r0 = base + (unsigned)(y0c * wl) * 256u;
            unsigned int r1 = base + (unsigned)(y1c * wl) * 256u;
            unsigned int* pd = &s_pd[wv][(unsigned)(pt * 8 + h) * 8u];
            pd[0] = r0 + (unsigned)x0c * 256u;
            pd[1] = r0 + (unsigned)x1c * 256u;
            pd[2] = r1 + (unsigned)x0c * 256u;
            pd[3] = r1 + (unsigned)x1c * 256u;
            float* pw = (float*)(pd + 4);
            pw[0] = w00; pw[1] = w10; pw[2] = w01; pw[3] = w11;
        }
    }
    __syncthreads();
    if (n >= N_TOK) return;

    int h = lane >> 3, dq = lane & 7;
    unsigned int colo = (unsigned)(dq * 4);
    float a0 = 0.f, a1 = 0.f, a2 = 0.f, a3 = 0.f;

    #pragma unroll 4
    for (int pt = 0; pt < 16; ++pt) {
        const unsigned int* pd = &s_pd[wv][(unsigned)(pt * 8 + h) * 8u];
        uint4 ad = *(const uint4*)pd;
        float4 wt = *(const float4*)(pd + 4);
        float4 v00 = *(const float4*)(value + ad.x + colo);
        float4 v10 = *(const float4*)(value + ad.y + colo);
        float4 v01 = *(const float4*)(value + ad.z + colo);
        float4 v11 = *(const float4*)(value + ad.w + colo);
        a0 += wt.x * v00.x + wt.y * v10.x + wt.z * v01.x + wt.w * v11.x;
        a1 += wt.x * v00.y + wt.y * v10.y + wt.z * v01.y + wt.w * v11.y;
        a2 += wt.x * v00.z + wt.y * v10.z + wt.z * v01.z + wt.w * v11.z;
        a3 += wt.x * v00.w + wt.y * v10.w + wt.z * v01.w + wt.w * v11.w;
    }
    u16 o[4] = { f2bf(a0), f2bf(a1), f2bf(a2), f2bf(a3) };
    *(ushort4*)(out + (size_t)n * 256 + h * 32 + dq * 4) = *(ushort4*)o;
}

extern "C" void kernel_launch(void* const* d_in, const int* in_sizes, int n_in,
                              void* d_out, int out_size, void* d_ws, size_t ws_size,
                              hipStream_t stream) {
    const float* src    = (const float*)d_in[0];
    const float* pos    = (const float*)d_in[1];
    const float* refp   = (const float*)d_in[2];
    const float* w_value= (const float*)d_in[3];
    const float* b_value= (const float*)d_in[4];
    const float* w_off  = (const float*)d_in[5];
    const float* b_off  = (const float*)d_in[6];
    const float* w_attn = (const float*)d_in[7];
    const float* b_attn = (const float*)d_in[8];
    const float* w_out  = (const float*)d_in[9];
    const float* b_out  = (const float*)d_in[10];
    const float* ln1_g  = (const float*)d_in[11];
    const float* ln1_b  = (const float*)d_in[12];
    const float* w1     = (const float*)d_in[13];
    const float* b1     = (const float*)d_in[14];
    const float* w2     = (const float*)d_in[15];
    const float* b2     = (const float*)d_in[16];
    const float* ln2_g  = (const float*)d_in[17];
    const float* ln2_b  = (const float*)d_in[18];

    // ws layout (bytes), liveness-packed:
    //   Vf   [0,        23046144)  f32 value          -> dead after ms_sample
    //   OA   [23046144, 57615360)  f32 off|attn       -> dead after ms_sample
    //   srcb [57615360, 69138432)  bf16 src           -> dead after value GEMM
    //   qb   [69138432, 80661504)  bf16 q; then Sb    -> dead after out-proj
    //   X    = Vf overlay (f32 LN1 out)
    //   Xb   = OA head overlay (bf16 LN1 out)
    //   Hb   [34569216, 80661504)  bf16 FFN hidden
    //   weights [80661504, ...)
    char* w = (char*)d_ws;
    float* Vf   = (float*)w;
    float* OA   = (float*)(w + 23046144);
    u16*   srcb = (u16*)(w + 57615360);
    u16*   qb   = (u16*)(w + 69138432);
    u16*   Sb   = qb;
    float* X    = (float*)w;
    u16*   Xb   = (u16*)(w + 23046144);
    u16*   Hb   = (u16*)(w + 34569216);
    char*  WB   = w + 80661504;
    u16* wv_t   = (u16*)WB;
    u16* woa_t  = wv_t + 65536;
    u16* wout_t = woa_t + 98304;
    u16* w1_t   = wout_t + 65536;
    u16* w2_t   = w1_t + 262144;
    float* boa  = (float*)(w2_t + 262144);
    float* out  = (float*)d_out;

    const size_t NV = (size_t)N_TOK * 256;
    dim3 blk(256);

    wprep<<<dim3(2946), blk, 0, stream>>>(w_value, w_off, w_attn, w_out, w1, w2,
                                          b_off, b_attn, wv_t, woa_t, wout_t, w1_t, w2_t, boa);
    cvt_src<<<dim3((int)(NV / 4 + 255) / 256), blk, 0, stream>>>(src, pos, srcb, qb, (int)(NV / 4));

    int MB = (N_TOK + BMT - 1) / BMT;  // 176
    // value = src @ w_value + b -> f32
    gemm_mfma<<<dim3(2, MB), blk, 0, stream>>>(srcb, wv_t, b_value, Vf, nullptr, N_TOK, 256, 256, 0);
    // [off|attn] = q @ [w_off|w_attn] + b -> f32
    gemm_mfma<<<dim3(3, MB), blk, 0, stream>>>(qb, woa_t, boa, OA, nullptr, N_TOK, 384, 256, 0);
    // sampling (fused softmax) -> Sb bf16 (reuses qb)
    ms_sample<<<dim3((N_TOK + 3) / 4), blk, 0, stream>>>(Vf, OA, refp, Sb);
    // x = LN1(src + S @ w_out + b_out) -> X f32, Xb bf16
    gemm_ln<<<dim3((N_TOK + 63) / 64), blk, 0, stream>>>(Sb, wout_t, b_out, src,
                                                         ln1_g, ln1_b, X, Xb, N_TOK, 256);
    // hidden = relu(x @ w1 + b1) -> Hb bf16
    gemm_mfma<<<dim3(8, MB), blk, 0, stream>>>(Xb, w1_t, b1, nullptr, Hb, N_TOK, 1024, 256, 1);
    // out = LN2(x + hidden @ w2 + b2) -> d_out f32
    gemm_ln<<<dim3((N_TOK + 63) / 64), blk, 0, stream>>>(Hb, w2_t, b2, X,
                                                         ln2_g, ln2_b, out, nullptr, N_TOK, 1024);
}

// Round 5
// 235.145 us; speedup vs baseline: 5.3577x; 1.0348x over previous
//
#include <hip/hip_runtime.h>
#include <hip/hip_bf16.h>
#include <math.h>

#define N_TOK 22506
#define LEN   11253
#define BKT 64
#define BMT 128

typedef unsigned short u16;
typedef __attribute__((ext_vector_type(8))) short short8;
typedef __attribute__((ext_vector_type(4))) float f32x4;

#define GLOAD16(g, l) __builtin_amdgcn_global_load_lds( \
    (const __attribute__((address_space(1))) void*)(g), \
    (__attribute__((address_space(3))) void*)(l), 16, 0, 0)

static __device__ __forceinline__ u16 f2bf(float f) {
    unsigned int u = __builtin_bit_cast(unsigned int, f);
    u = (u + 0x7fffu + ((u >> 16) & 1u)) >> 16;
    return (u16)u;
}
static __device__ __forceinline__ float bflo(unsigned int u) {
    return __builtin_bit_cast(float, u << 16);
}
static __device__ __forceinline__ float bfhi(unsigned int u) {
    return __builtin_bit_cast(float, u & 0xffff0000u);
}

// ---- all weight transposes (f32 -> bf16, [K][N] -> [N][K]) + bias concat ----
__global__ __launch_bounds__(256) void wprep(
    const float* __restrict__ w_value, const float* __restrict__ w_off,
    const float* __restrict__ w_attn, const float* __restrict__ w_out,
    const float* __restrict__ w1, const float* __restrict__ w2,
    const float* __restrict__ b_off, const float* __restrict__ b_attn,
    u16* __restrict__ wv_t, u16* __restrict__ woa_t, u16* __restrict__ wout_t,
    u16* __restrict__ w1_t, u16* __restrict__ w2_t, float* __restrict__ boa)
{
    int i = blockIdx.x * 256 + threadIdx.x;
    if (i < 65536) {
        wv_t[(i & 255) * 256 + (i >> 8)] = f2bf(w_value[i]);
    } else if (i < 131072) {
        int j = i - 65536;
        woa_t[(j & 255) * 256 + (j >> 8)] = f2bf(w_off[j]);
    } else if (i < 163840) {
        int j = i - 131072;
        woa_t[65536 + (j & 127) * 256 + (j >> 7)] = f2bf(w_attn[j]);
    } else if (i < 229376) {
        int j = i - 163840;
        wout_t[(j & 255) * 256 + (j >> 8)] = f2bf(w_out[j]);
    } else if (i < 491520) {
        int j = i - 229376;
        w1_t[(j & 1023) * 256 + (j >> 10)] = f2bf(w1[j]);
    } else if (i < 753664) {
        int j = i - 491520;
        w2_t[(j & 255) * 1024 + (j >> 8)] = f2bf(w2[j]);
    } else if (i < 754048) {
        int j = i - 753664;
        boa[j] = (j < 256) ? b_off[j] : b_attn[j - 256];
    }
}

// ---- fused value + off/attn GEMM. A converted f32->bf16 in staging.
// grid.x in [0,5): x<2 -> value job (col block x), else off|attn job (x-2).
__global__ __launch_bounds__(256) void gemm_qv(
    const float* __restrict__ src, const float* __restrict__ pos,
    const u16* __restrict__ wv_t, const u16* __restrict__ woa_t,
    const float* __restrict__ b_value, const float* __restrict__ boa,
    u16* __restrict__ Vb, float* __restrict__ OA)
{
    __shared__ u16 As[BMT * BKT];
    __shared__ u16 Bs[BMT * BKT];
    int tid = threadIdx.x;
    int lane = tid & 63, wid = tid >> 6;
    int wr = wid >> 1, wc = wid & 1;
    int job = blockIdx.x < 2 ? 0 : 1;
    int bn = job ? (int)(blockIdx.x - 2) * 128 : (int)blockIdx.x * 128;
    const u16* Bt = job ? woa_t : wv_t;
    int bm = blockIdx.y * BMT;

    f32x4 acc[4][4] = {};
    int sr = tid >> 3, ss = tid & 7;
    int gcol = (((lane & 7) ^ (lane >> 3)) << 3);

    for (int k0 = 0; k0 < 256; k0 += BKT) {
        #pragma unroll
        for (int i = 0; i < 4; ++i) {
            int r = i * 32 + sr;
            int gr = bm + r;
            short8 v = {0,0,0,0,0,0,0,0};
            if (gr < N_TOK) {
                const float* sp = src + (size_t)gr * 256 + k0 + ss * 8;
                float4 a0 = *(const float4*)sp;
                float4 a1 = *(const float4*)(sp + 4);
                if (job) {
                    const float* pp = pos + (size_t)gr * 256 + k0 + ss * 8;
                    float4 p0 = *(const float4*)pp;
                    float4 p1 = *(const float4*)(pp + 4);
                    a0.x += p0.x; a0.y += p0.y; a0.z += p0.z; a0.w += p0.w;
                    a1.x += p1.x; a1.y += p1.y; a1.z += p1.z; a1.w += p1.w;
                }
                u16 tt[8] = { f2bf(a0.x), f2bf(a0.y), f2bf(a0.z), f2bf(a0.w),
                              f2bf(a1.x), f2bf(a1.y), f2bf(a1.z), f2bf(a1.w) };
                v = *(short8*)tt;
            }
            *(short8*)(&As[r * BKT + ((ss ^ (r & 7)) << 3)]) = v;
        }
        #pragma unroll
        for (int i = 0; i < 4; ++i) {
            int rb = wid * 32 + i * 8;
            GLOAD16(Bt + (size_t)(bn + rb + (lane >> 3)) * 256 + k0 + gcol, &Bs[rb * BKT]);
        }
        __syncthreads();

        int rlo = lane & 15, khalf = lane >> 4;
        short8 af[4][2], bfr[4][2];
        #pragma unroll
        for (int mi = 0; mi < 4; ++mi) {
            int row = wr * 64 + mi * 16 + rlo;
            #pragma unroll
            for (int kk = 0; kk < 2; ++kk) {
                int slot = khalf + kk * 4;
                af[mi][kk] = *(const short8*)(&As[row * BKT + ((slot ^ (row & 7)) << 3)]);
            }
        }
        #pragma unroll
        for (int ni = 0; ni < 4; ++ni) {
            int col = wc * 64 + ni * 16 + rlo;
            #pragma unroll
            for (int kk = 0; kk < 2; ++kk) {
                int slot = khalf + kk * 4;
                bfr[ni][kk] = *(const short8*)(&Bs[col * BKT + ((slot ^ (col & 7)) << 3)]);
            }
        }
        #pragma unroll
        for (int mi = 0; mi < 4; ++mi)
            #pragma unroll
            for (int ni = 0; ni < 4; ++ni)
                #pragma unroll
                for (int kk = 0; kk < 2; ++kk)
                    acc[mi][ni] = __builtin_amdgcn_mfma_f32_16x16x32_bf16(
                        af[mi][kk], bfr[ni][kk], acc[mi][ni], 0, 0, 0);
        __syncthreads();
    }

    int col_l = lane & 15, rgrp = lane >> 4;
    #pragma unroll
    for (int mi = 0; mi < 4; ++mi) {
        #pragma unroll
        for (int j = 0; j < 4; ++j) {
            int row = bm + wr * 64 + mi * 16 + rgrp * 4 + j;
            if (row >= N_TOK) continue;
            #pragma unroll
            for (int ni = 0; ni < 4; ++ni) {
                int col = bn + wc * 64 + ni * 16 + col_l;
                if (job) {
                    OA[(size_t)row * 384 + col] = acc[mi][ni][j] + boa[col];
                } else {
                    Vb[(size_t)row * 256 + col] = f2bf(acc[mi][ni][j] + b_value[col]);
                }
            }
        }
    }
}

// ---- generic bf16 MFMA GEMM (128x128 tile), global_load_lds staging ----
__global__ __launch_bounds__(256) void gemm_mfma(
    const u16* __restrict__ A, const u16* __restrict__ Bt,
    const float* __restrict__ bias, float* __restrict__ Cf, u16* __restrict__ Cb,
    int M, int Nc, int K, int relu)
{
    __shared__ u16 As[BMT * BKT];
    __shared__ u16 Bs[BMT * BKT];
    int tid = threadIdx.x;
    int lane = tid & 63, wid = tid >> 6;
    int wr = wid >> 1, wc = wid & 1;
    int bm = blockIdx.y * BMT, bn = blockIdx.x * BMT;

    f32x4 acc[4][4] = {};
    int gcol = (((lane & 7) ^ (lane >> 3)) << 3);

    for (int k0 = 0; k0 < K; k0 += BKT) {
        #pragma unroll
        for (int i = 0; i < 4; ++i) {
            int rb = wid * 32 + i * 8;
            GLOAD16(A  + (size_t)(bm + rb + (lane >> 3)) * K + k0 + gcol, &As[rb * BKT]);
            GLOAD16(Bt + (size_t)(bn + rb + (lane >> 3)) * K + k0 + gcol, &Bs[rb * BKT]);
        }
        __syncthreads();

        int rlo = lane & 15, khalf = lane >> 4;
        short8 af[4][2], bfr[4][2];
        #pragma unroll
        for (int mi = 0; mi < 4; ++mi) {
            int row = wr * 64 + mi * 16 + rlo;
            #pragma unroll
            for (int kk = 0; kk < 2; ++kk) {
                int slot = khalf + kk * 4;
                af[mi][kk] = *(const short8*)(&As[row * BKT + ((slot ^ (row & 7)) << 3)]);
            }
        }
        #pragma unroll
        for (int ni = 0; ni < 4; ++ni) {
            int col = wc * 64 + ni * 16 + rlo;
            #pragma unroll
            for (int kk = 0; kk < 2; ++kk) {
                int slot = khalf + kk * 4;
                bfr[ni][kk] = *(const short8*)(&Bs[col * BKT + ((slot ^ (col & 7)) << 3)]);
            }
        }
        #pragma unroll
        for (int mi = 0; mi < 4; ++mi)
            #pragma unroll
            for (int ni = 0; ni < 4; ++ni)
                #pragma unroll
                for (int kk = 0; kk < 2; ++kk)
                    acc[mi][ni] = __builtin_amdgcn_mfma_f32_16x16x32_bf16(
                        af[mi][kk], bfr[ni][kk], acc[mi][ni], 0, 0, 0);
        __syncthreads();
    }

    int col_l = lane & 15, rgrp = lane >> 4;
    #pragma unroll
    for (int mi = 0; mi < 4; ++mi) {
        #pragma unroll
        for (int j = 0; j < 4; ++j) {
            int row = bm + wr * 64 + mi * 16 + rgrp * 4 + j;
            if (row >= M) continue;
            #pragma unroll
            for (int ni = 0; ni < 4; ++ni) {
                int col = bn + wc * 64 + ni * 16 + col_l;
                float v = acc[mi][ni][j];
                if (bias) v += bias[col];
                if (relu) v = fmaxf(v, 0.f);
                if (Cf) Cf[(size_t)row * Nc + col] = v;
                if (Cb) Cb[(size_t)row * Nc + col] = f2bf(v);
            }
        }
    }
}

// ---- Nc=256 GEMM + fused residual-add + LayerNorm, global_load_lds staging ----
__global__ __launch_bounds__(256) void gemm_ln(
    const u16* __restrict__ A, const u16* __restrict__ Bt,
    const float* __restrict__ bias, const float* __restrict__ res,
    const float* __restrict__ g, const float* __restrict__ beta,
    float* __restrict__ outf, u16* __restrict__ outb,
    int M, int K)
{
    __shared__ u16 As[64 * BKT];      // 8 KB
    __shared__ u16 Bs[256 * BKT];     // 32 KB
    int tid = threadIdx.x;
    int lane = tid & 63, wc = tid >> 6;
    int bm = blockIdx.x * 64;
    f32x4 acc[4][4] = {};
    int gcol = (((lane & 7) ^ (lane >> 3)) << 3);

    for (int k0 = 0; k0 < K; k0 += BKT) {
        #pragma unroll
        for (int i = 0; i < 2; ++i) {
            int ra = wc * 16 + i * 8;
            GLOAD16(A + (size_t)(bm + ra + (lane >> 3)) * K + k0 + gcol, &As[ra * BKT]);
        }
        #pragma unroll
        for (int i = 0; i < 8; ++i) {
            int rb = wc * 64 + i * 8;
            GLOAD16(Bt + (size_t)(rb + (lane >> 3)) * K + k0 + gcol, &Bs[rb * BKT]);
        }
        __syncthreads();

        int rlo = lane & 15, khalf = lane >> 4;
        short8 af[4][2], bfr[4][2];
        #pragma unroll
        for (int mi = 0; mi < 4; ++mi) {
            int row = mi * 16 + rlo;
            #pragma unroll
            for (int kk = 0; kk < 2; ++kk) {
                int slot = khalf + kk * 4;
                af[mi][kk] = *(const short8*)(&As[row * BKT + ((slot ^ (row & 7)) << 3)]);
            }
        }
        #pragma unroll
        for (int ni = 0; ni < 4; ++ni) {
            int col = wc * 64 + ni * 16 + rlo;
            #pragma unroll
            for (int kk = 0; kk < 2; ++kk) {
                int slot = khalf + kk * 4;
                bfr[ni][kk] = *(const short8*)(&Bs[col * BKT + ((slot ^ (col & 7)) << 3)]);
            }
        }
        #pragma unroll
        for (int mi = 0; mi < 4; ++mi)
            #pragma unroll
            for (int ni = 0; ni < 4; ++ni)
                #pragma unroll
                for (int kk = 0; kk < 2; ++kk)
                    acc[mi][ni] = __builtin_amdgcn_mfma_f32_16x16x32_bf16(
                        af[mi][kk], bfr[ni][kk], acc[mi][ni], 0, 0, 0);
        __syncthreads();
    }

    float* red = (float*)As;
    int col_l = lane & 15, rgrp = lane >> 4;
    int colc[4]; float bias_c[4], g_c[4], be_c[4];
    #pragma unroll
    for (int ni = 0; ni < 4; ++ni) {
        colc[ni] = wc * 64 + ni * 16 + col_l;
        bias_c[ni] = bias[colc[ni]];
        g_c[ni]  = g[colc[ni]];
        be_c[ni] = beta[colc[ni]];
    }
    #pragma unroll
    for (int mi = 0; mi < 4; ++mi) {
        #pragma unroll
        for (int j = 0; j < 4; ++j) {
            int rl = mi * 16 + rgrp * 4 + j;
            int row = bm + rl;
            float s = 0.f, s2 = 0.f;
            if (row < M) {
                #pragma unroll
                for (int ni = 0; ni < 4; ++ni) {
                    float v = acc[mi][ni][j] + bias_c[ni] + res[(size_t)row * 256 + colc[ni]];
                    acc[mi][ni][j] = v;
                    s += v; s2 += v * v;
                }
            }
            #pragma unroll
            for (int d = 1; d < 16; d <<= 1) { s += __shfl_xor(s, d); s2 += __shfl_xor(s2, d); }
            if (col_l == 0) { red[wc * 64 + rl] = s; red[256 + wc * 64 + rl] = s2; }
        }
    }
    __syncthreads();
    if (tid < 64) {
        float s  = red[tid] + red[64 + tid] + red[128 + tid] + red[192 + tid];
        float s2 = red[256 + tid] + red[320 + tid] + red[384 + tid] + red[448 + tid];
        float mean = s * (1.f / 256.f);
        float var = s2 * (1.f / 256.f) - mean * mean;
        red[512 + tid] = mean;
        red[576 + tid] = rsqrtf(var + 1e-5f);
    }
    __syncthreads();
    #pragma unroll
    for (int mi = 0; mi < 4; ++mi) {
        #pragma unroll
        for (int j = 0; j < 4; ++j) {
            int rl = mi * 16 + rgrp * 4 + j;
            int row = bm + rl;
            if (row >= M) continue;
            float mean = red[512 + rl], rs = red[576 + rl];
            #pragma unroll
            for (int ni = 0; ni < 4; ++ni) {
                float o = g_c[ni] * (acc[mi][ni][j] - mean) * rs + be_c[ni];
                outf[(size_t)row * 256 + colc[ni]] = o;
                if (outb) outb[(size_t)row * 256 + colc[ni]] = f2bf(o);
            }
        }
    }
}

// ---- deformable sampling, phase-split, bf16 value, XOR-permuted LDS ----
__global__ __launch_bounds__(256) void ms_sample(
    const u16* __restrict__ value, const float* __restrict__ oa,
    const float* __restrict__ refp, u16* __restrict__ out)
{
    const int starts[4] = {0, 8464, 10580, 11109};
    const int sizes[4]  = {92, 46, 23, 12};
    int t = threadIdx.x;
    int wv = t >> 6, lane = t & 63;
    int n = blockIdx.x * 4 + wv;

    __shared__ uint4  s_ad[4][128];   // 8 KB
    __shared__ float4 s_wt[4][128];   // 8 KB

    if (n < N_TOK) {
        const float* oan = oa + (size_t)n * 384;
        unsigned int tokbase = (n >= LEN) ? (unsigned)LEN : 0u;
        #pragma unroll
        for (int rep = 0; rep < 2; ++rep) {
            int q = rep * 64 + lane;          // q = h*16 + pt
            int h = q >> 4, pt = q & 15, l = pt >> 2;
            float logit = oan[256 + q];
            float m = logit;
            #pragma unroll
            for (int d = 1; d < 16; d <<= 1) m = fmaxf(m, __shfl_xor(m, d));
            float e = expf(logit - m);
            float ssum = e;
            #pragma unroll
            for (int d = 1; d < 16; d <<= 1) ssum += __shfl_xor(ssum, d);
            float aw = e / ssum;
            float2 off2 = *(const float2*)(oan + 2 * q);
            float2 ref2 = *(const float2*)(refp + (size_t)n * 8 + l * 2);
            int wl = sizes[l];
            float wf = (float)wl;
            float x = ref2.x * wf - 0.5f + off2.x;
            float y = ref2.y * wf - 0.5f + off2.y;
            float x0f = floorf(x), y0f = floorf(y);
            float fx = x - x0f, fy = y - y0f;
            int x0 = (int)x0f, y0 = (int)y0f;
            int x1 = x0 + 1, y1 = y0 + 1;
            float gx = 1.f - fx, gy = 1.f - fy;
            bool bx0 = (unsigned)x0 < (unsigned)wl, bx1 = (unsigned)x1 < (unsigned)wl;
            bool by0 = (unsigned)y0 < (unsigned)wl, by1 = (unsigned)y1 < (unsigned)wl;
            float w00 = (bx0 && by0) ? gx * gy * aw : 0.f;
            float w10 = (bx1 && by0) ? fx * gy * aw : 0.f;
            float w01 = (bx0 && by1) ? gx * fy * aw : 0.f;
            float w11 = (bx1 && by1) ? fx * fy * aw : 0.f;
            int x0c = min(max(x0, 0), wl - 1), x1c = min(max(x1, 0), wl - 1);
            int y0c = min(max(y0, 0), wl - 1), y1c = min(max(y1, 0), wl - 1);
            unsigned int base = (tokbase + (unsigned)starts[l]) * 256u + (unsigned)(h * 32);
            unsigned int r0 = base + (unsigned)(y0c * wl) * 256u;
            unsigned int r1 = base + (unsigned)(y1c * wl) * 256u;
            int idx = pt * 8 + (h ^ (pt & 7));
            s_ad[wv][idx] = make_uint4(r0 + (unsigned)x0c * 256u, r0 + (unsigned)x1c * 256u,
                                       r1 + (unsigned)x0c * 256u, r1 + (unsigned)x1c * 256u);
            s_wt[wv][idx] = make_float4(w00, w10, w01, w11);
        }
    }
    __syncthreads();
    if (n >= N_TOK) return;

    int h = lane >> 3, dq = lane & 7;
    unsigned int colo = (unsigned)(dq * 4);
    float a0 = 0.f, a1 = 0.f, a2 = 0.f, a3 = 0.f;

    #pragma unroll 8
    for (int pt = 0; pt < 16; ++pt) {
        int idx = pt * 8 + (h ^ (pt & 7));
        uint4 ad = s_ad[wv][idx];
        float4 wt = s_wt[wv][idx];
        uint2 u00 = *(const uint2*)(value + ad.x + colo);
        uint2 u10 = *(const uint2*)(value + ad.y + colo);
        uint2 u01 = *(const uint2*)(value + ad.z + colo);
        uint2 u11 = *(const uint2*)(value + ad.w + colo);
        a0 += wt.x * bflo(u00.x) + wt.y * bflo(u10.x) + wt.z * bflo(u01.x) + wt.w * bflo(u11.x);
        a1 += wt.x * bfhi(u00.x) + wt.y * bfhi(u10.x) + wt.z * bfhi(u01.x) + wt.w * bfhi(u11.x);
        a2 += wt.x * bflo(u00.y) + wt.y * bflo(u10.y) + wt.z * bflo(u01.y) + wt.w * bflo(u11.y);
        a3 += wt.x * bfhi(u00.y) + wt.y * bfhi(u10.y) + wt.z * bfhi(u01.y) + wt.w * bfhi(u11.y);
    }
    u16 o[4] = { f2bf(a0), f2bf(a1), f2bf(a2), f2bf(a3) };
    *(ushort4*)(out + (size_t)n * 256 + h * 32 + dq * 4) = *(ushort4*)o;
}

extern "C" void kernel_launch(void* const* d_in, const int* in_sizes, int n_in,
                              void* d_out, int out_size, void* d_ws, size_t ws_size,
                              hipStream_t stream) {
    const float* src    = (const float*)d_in[0];
    const float* pos    = (const float*)d_in[1];
    const float* refp   = (const float*)d_in[2];
    const float* w_value= (const float*)d_in[3];
    const float* b_value= (const float*)d_in[4];
    const float* w_off  = (const float*)d_in[5];
    const float* b_off  = (const float*)d_in[6];
    const float* w_attn = (const float*)d_in[7];
    const float* b_attn = (const float*)d_in[8];
    const float* w_out  = (const float*)d_in[9];
    const float* b_out  = (const float*)d_in[10];
    const float* ln1_g  = (const float*)d_in[11];
    const float* ln1_b  = (const float*)d_in[12];
    const float* w1     = (const float*)d_in[13];
    const float* b1     = (const float*)d_in[14];
    const float* w2     = (const float*)d_in[15];
    const float* b2     = (const float*)d_in[16];
    const float* ln2_g  = (const float*)d_in[17];
    const float* ln2_b  = (const float*)d_in[18];

    // ws layout (bytes):
    //   Vb  [0,          11523072)  bf16 value        } dead after ms_sample
    //   OA  [11523072,   46092288)  f32 off|attn      }
    //   X   [0,          23046144)  f32 LN1 out   (overlays Vb/OA after death)
    //   Xb  [23046144,   34569216)  bf16 LN1 out  (overlay)
    //   Sb  [46092288,   57615360)  bf16 sampled
    //   Hb  [57615360,  103707648)  bf16 FFN hidden
    //   weights [103707648, 105216512)
    char* w = (char*)d_ws;
    u16*   Vb = (u16*)w;
    float* OA = (float*)(w + 11523072);
    float* X  = (float*)w;
    u16*   Xb = (u16*)(w + 23046144);
    u16*   Sb = (u16*)(w + 46092288);
    u16*   Hb = (u16*)(w + 57615360);
    char*  WB = w + 103707648;
    u16* wv_t   = (u16*)WB;
    u16* woa_t  = wv_t + 65536;
    u16* wout_t = woa_t + 98304;
    u16* w1_t   = wout_t + 65536;
    u16* w2_t   = w1_t + 262144;
    float* boa  = (float*)(w2_t + 262144);
    float* out  = (float*)d_out;

    dim3 blk(256);
    int MB = (N_TOK + BMT - 1) / BMT;  // 176

    wprep<<<dim3(2946), blk, 0, stream>>>(w_value, w_off, w_attn, w_out, w1, w2,
                                          b_off, b_attn, wv_t, woa_t, wout_t, w1_t, w2_t, boa);
    // value(bf16) + [off|attn](f32) in one dispatch
    gemm_qv<<<dim3(5, MB), blk, 0, stream>>>(src, pos, wv_t, woa_t, b_value, boa, Vb, OA);
    // sampling (fused softmax) -> Sb bf16
    ms_sample<<<dim3((N_TOK + 3) / 4), blk, 0, stream>>>(Vb, OA, refp, Sb);
    // x = LN1(src + S @ w_out + b_out) -> X f32, Xb bf16
    gemm_ln<<<dim3((N_TOK + 63) / 64), blk, 0, stream>>>(Sb, wout_t, b_out, src,
                                                         ln1_g, ln1_b, X, Xb, N_TOK, 256);
    // hidden = relu(x @ w1 + b1) -> Hb bf16
    gemm_mfma<<<dim3(8, MB), blk, 0, stream>>>(Xb, w1_t, b1, nullptr, Hb, N_TOK, 1024, 256, 1);
    // out = LN2(x + hidden @ w2 + b2) -> d_out f32
    gemm_ln<<<dim3((N_TOK + 63) / 64), blk, 0, stream>>>(Hb, w2_t, b2, X,
                                                         ln2_g, ln2_b, out, nullptr, N_TOK, 1024);
}

// Round 6
// 214.673 us; speedup vs baseline: 5.8686x; 1.0954x over previous
//
#include <hip/hip_runtime.h>
#include <hip/hip_bf16.h>
#include <math.h>

#define N_TOK 22506
#define LEN   11253
#define BKT 64
#define BMT 128

typedef unsigned short u16;
typedef __attribute__((ext_vector_type(8))) short short8;
typedef __attribute__((ext_vector_type(4))) float f32x4;

#define GLOAD16(g, l) __builtin_amdgcn_global_load_lds( \
    (const __attribute__((address_space(1))) void*)(g), \
    (__attribute__((address_space(3))) void*)(l), 16, 0, 0)

static __device__ __forceinline__ u16 f2bf(float f) {
    unsigned int u = __builtin_bit_cast(unsigned int, f);
    u = (u + 0x7fffu + ((u >> 16) & 1u)) >> 16;
    return (u16)u;
}
static __device__ __forceinline__ float bflo(unsigned int u) {
    return __builtin_bit_cast(float, u << 16);
}
static __device__ __forceinline__ float bfhi(unsigned int u) {
    return __builtin_bit_cast(float, u & 0xffff0000u);
}

// bijective XCD-chunked swizzle (m204): blocks on one XCD get contiguous work ids
static __device__ __forceinline__ int xcd_swz(int id, int nwg) {
    int q = nwg >> 3, r = nwg & 7;
    int xcd = id & 7, rank = id >> 3;
    return (xcd < r ? xcd * (q + 1) : r * (q + 1) + (xcd - r) * q) + rank;
}

// ---- all weight transposes (f32 -> bf16, [K][N] -> [N][K]) + bias concat ----
__global__ __launch_bounds__(256) void wprep(
    const float* __restrict__ w_value, const float* __restrict__ w_off,
    const float* __restrict__ w_attn, const float* __restrict__ w_out,
    const float* __restrict__ w1, const float* __restrict__ w2,
    const float* __restrict__ b_off, const float* __restrict__ b_attn,
    u16* __restrict__ wv_t, u16* __restrict__ woa_t, u16* __restrict__ wout_t,
    u16* __restrict__ w1_t, u16* __restrict__ w2_t, float* __restrict__ boa)
{
    int i = blockIdx.x * 256 + threadIdx.x;
    if (i < 65536) {
        wv_t[(i & 255) * 256 + (i >> 8)] = f2bf(w_value[i]);
    } else if (i < 131072) {
        int j = i - 65536;
        woa_t[(j & 255) * 256 + (j >> 8)] = f2bf(w_off[j]);
    } else if (i < 163840) {
        int j = i - 131072;
        woa_t[65536 + (j & 127) * 256 + (j >> 7)] = f2bf(w_attn[j]);
    } else if (i < 229376) {
        int j = i - 163840;
        wout_t[(j & 255) * 256 + (j >> 8)] = f2bf(w_out[j]);
    } else if (i < 491520) {
        int j = i - 229376;
        w1_t[(j & 1023) * 256 + (j >> 10)] = f2bf(w1[j]);
    } else if (i < 753664) {
        int j = i - 491520;
        w2_t[(j & 255) * 1024 + (j >> 8)] = f2bf(w2[j]);
    } else if (i < 754048) {
        int j = i - 753664;
        boa[j] = (j < 256) ? b_off[j] : b_attn[j - 256];
    }
}

// ---- fused value + off/attn GEMM, double-buffered (async A-reg split + GLOAD16 B) ----
// grid.x in [0,5): x<2 -> value job (col block x), else off|attn job (x-2).
__global__ __launch_bounds__(256) void gemm_qv(
    const float* __restrict__ src, const float* __restrict__ pos,
    const u16* __restrict__ wv_t, const u16* __restrict__ woa_t,
    const float* __restrict__ b_value, const float* __restrict__ boa,
    u16* __restrict__ Vb, float* __restrict__ OA)
{
    __shared__ u16 As[2][BMT * BKT];
    __shared__ u16 Bs[2][BMT * BKT];
    int tid = threadIdx.x;
    int lane = tid & 63, wid = tid >> 6;
    int wr = wid >> 1, wc = wid & 1;

    int nwg = gridDim.x * gridDim.y;
    int sid = xcd_swz(blockIdx.y * gridDim.x + blockIdx.x, nwg);
    int bxx = sid % 5, byy = sid / 5;
    int job = bxx < 2 ? 0 : 1;
    int bn = job ? (bxx - 2) * 128 : bxx * 128;
    const u16* Bt = job ? woa_t : wv_t;
    int bm = byy * BMT;

    f32x4 acc[4][4] = {};
    int sr = tid >> 3, ss = tid & 7;
    int grow = lane >> 3;
    int gcol = (((lane & 7) ^ grow) << 3);

    float4 a0[4], a1[4];   // staged A rows (f32), one 8-float strip per i

    auto loadA = [&](int k0) {
        #pragma unroll
        for (int i = 0; i < 4; ++i) {
            int gr = bm + i * 32 + sr;
            if (gr < N_TOK) {
                const float* sp = src + (size_t)gr * 256 + k0 + ss * 8;
                a0[i] = *(const float4*)sp;
                a1[i] = *(const float4*)(sp + 4);
                if (job) {
                    const float* pp = pos + (size_t)gr * 256 + k0 + ss * 8;
                    float4 p0 = *(const float4*)pp;
                    float4 p1 = *(const float4*)(pp + 4);
                    a0[i].x += p0.x; a0[i].y += p0.y; a0[i].z += p0.z; a0[i].w += p0.w;
                    a1[i].x += p1.x; a1[i].y += p1.y; a1[i].z += p1.z; a1[i].w += p1.w;
                }
            } else {
                a0[i] = make_float4(0.f, 0.f, 0.f, 0.f);
                a1[i] = make_float4(0.f, 0.f, 0.f, 0.f);
            }
        }
    };
    auto writeA = [&](int b) {
        #pragma unroll
        for (int i = 0; i < 4; ++i) {
            int r = i * 32 + sr;
            u16 tt[8] = { f2bf(a0[i].x), f2bf(a0[i].y), f2bf(a0[i].z), f2bf(a0[i].w),
                          f2bf(a1[i].x), f2bf(a1[i].y), f2bf(a1[i].z), f2bf(a1[i].w) };
            *(short8*)(&As[b][r * BKT + ((ss ^ (r & 7)) << 3)]) = *(short8*)tt;
        }
    };
    auto stageB = [&](int k0, int b) {
        #pragma unroll
        for (int i = 0; i < 4; ++i) {
            int rb = wid * 32 + i * 8;
            GLOAD16(Bt + (size_t)(bn + rb + grow) * 256 + k0 + gcol, &Bs[b][rb * BKT]);
        }
    };

    // prologue
    loadA(0);
    stageB(0, 0);
    writeA(0);
    __syncthreads();

    for (int t = 0; t < 4; ++t) {
        int cur = t & 1;
        if (t < 3) {
            loadA((t + 1) * BKT);          // issue early (hides under MFMA)
            stageB((t + 1) * BKT, cur ^ 1);
        }
        int rlo = lane & 15, khalf = lane >> 4;
        short8 af[4][2], bfr[4][2];
        #pragma unroll
        for (int mi = 0; mi < 4; ++mi) {
            int row = wr * 64 + mi * 16 + rlo;
            #pragma unroll
            for (int kk = 0; kk < 2; ++kk) {
                int slot = khalf + kk * 4;
                af[mi][kk] = *(const short8*)(&As[cur][row * BKT + ((slot ^ (row & 7)) << 3)]);
            }
        }
        #pragma unroll
        for (int ni = 0; ni < 4; ++ni) {
            int col = wc * 64 + ni * 16 + rlo;
            #pragma unroll
            for (int kk = 0; kk < 2; ++kk) {
                int slot = khalf + kk * 4;
                bfr[ni][kk] = *(const short8*)(&Bs[cur][col * BKT + ((slot ^ (col & 7)) << 3)]);
            }
        }
        #pragma unroll
        for (int mi = 0; mi < 4; ++mi)
            #pragma unroll
            for (int ni = 0; ni < 4; ++ni)
                #pragma unroll
                for (int kk = 0; kk < 2; ++kk)
                    acc[mi][ni] = __builtin_amdgcn_mfma_f32_16x16x32_bf16(
                        af[mi][kk], bfr[ni][kk], acc[mi][ni], 0, 0, 0);
        if (t < 3) writeA(cur ^ 1);        // waitcnt on A-regs lands here, after MFMA
        __syncthreads();
    }

    int col_l = lane & 15, rgrp = lane >> 4;
    #pragma unroll
    for (int mi = 0; mi < 4; ++mi) {
        #pragma unroll
        for (int j = 0; j < 4; ++j) {
            int row = bm + wr * 64 + mi * 16 + rgrp * 4 + j;
            if (row >= N_TOK) continue;
            #pragma unroll
            for (int ni = 0; ni < 4; ++ni) {
                int col = bn + wc * 64 + ni * 16 + col_l;
                if (job) {
                    OA[(size_t)row * 384 + col] = acc[mi][ni][j] + boa[col];
                } else {
                    Vb[(size_t)row * 256 + col] = f2bf(acc[mi][ni][j] + b_value[col]);
                }
            }
        }
    }
}

// ---- generic bf16 MFMA GEMM (128x128 tile), double-buffered GLOAD16 staging ----
__global__ __launch_bounds__(256) void gemm_mfma(
    const u16* __restrict__ A, const u16* __restrict__ Bt,
    const float* __restrict__ bias, float* __restrict__ Cf, u16* __restrict__ Cb,
    int M, int Nc, int K, int relu)
{
    __shared__ u16 As[2][BMT * BKT];
    __shared__ u16 Bs[2][BMT * BKT];
    int tid = threadIdx.x;
    int lane = tid & 63, wid = tid >> 6;
    int wr = wid >> 1, wc = wid & 1;

    int nwg = gridDim.x * gridDim.y;
    int sid = xcd_swz(blockIdx.y * gridDim.x + blockIdx.x, nwg);
    int bm = (sid / gridDim.x) * BMT, bn = (sid % gridDim.x) * BMT;

    f32x4 acc[4][4] = {};
    int grow = lane >> 3;
    int gcol = (((lane & 7) ^ grow) << 3);

    auto stage = [&](int k0, int b) {
        #pragma unroll
        for (int i = 0; i < 4; ++i) {
            int rb = wid * 32 + i * 8;
            GLOAD16(A  + (size_t)(bm + rb + grow) * K + k0 + gcol, &As[b][rb * BKT]);
            GLOAD16(Bt + (size_t)(bn + rb + grow) * K + k0 + gcol, &Bs[b][rb * BKT]);
        }
    };

    stage(0, 0);
    __syncthreads();
    int KT = K / BKT;
    for (int t = 0; t < KT; ++t) {
        int cur = t & 1;
        if (t + 1 < KT) stage((t + 1) * BKT, cur ^ 1);
        int rlo = lane & 15, khalf = lane >> 4;
        short8 af[4][2], bfr[4][2];
        #pragma unroll
        for (int mi = 0; mi < 4; ++mi) {
            int row = wr * 64 + mi * 16 + rlo;
            #pragma unroll
            for (int kk = 0; kk < 2; ++kk) {
                int slot = khalf + kk * 4;
                af[mi][kk] = *(const short8*)(&As[cur][row * BKT + ((slot ^ (row & 7)) << 3)]);
            }
        }
        #pragma unroll
        for (int ni = 0; ni < 4; ++ni) {
            int col = wc * 64 + ni * 16 + rlo;
            #pragma unroll
            for (int kk = 0; kk < 2; ++kk) {
                int slot = khalf + kk * 4;
                bfr[ni][kk] = *(const short8*)(&Bs[cur][col * BKT + ((slot ^ (col & 7)) << 3)]);
            }
        }
        #pragma unroll
        for (int mi = 0; mi < 4; ++mi)
            #pragma unroll
            for (int ni = 0; ni < 4; ++ni)
                #pragma unroll
                for (int kk = 0; kk < 2; ++kk)
                    acc[mi][ni] = __builtin_amdgcn_mfma_f32_16x16x32_bf16(
                        af[mi][kk], bfr[ni][kk], acc[mi][ni], 0, 0, 0);
        __syncthreads();
    }

    int col_l = lane & 15, rgrp = lane >> 4;
    #pragma unroll
    for (int mi = 0; mi < 4; ++mi) {
        #pragma unroll
        for (int j = 0; j < 4; ++j) {
            int row = bm + wr * 64 + mi * 16 + rgrp * 4 + j;
            if (row >= M) continue;
            #pragma unroll
            for (int ni = 0; ni < 4; ++ni) {
                int col = bn + wc * 64 + ni * 16 + col_l;
                float v = acc[mi][ni][j];
                if (bias) v += bias[col];
                if (relu) v = fmaxf(v, 0.f);
                if (Cf) Cf[(size_t)row * Nc + col] = v;
                if (Cb) Cb[(size_t)row * Nc + col] = f2bf(v);
            }
        }
    }
}

// ---- Nc=256 GEMM + fused residual-add + LayerNorm, double-buffered staging ----
__global__ __launch_bounds__(256) void gemm_ln(
    const u16* __restrict__ A, const u16* __restrict__ Bt,
    const float* __restrict__ bias, const float* __restrict__ res,
    const float* __restrict__ g, const float* __restrict__ beta,
    float* __restrict__ outf, u16* __restrict__ outb,
    int M, int K)
{
    __shared__ u16 As[2][64 * BKT];    // 16 KB
    __shared__ u16 Bs[2][256 * BKT];   // 64 KB
    int tid = threadIdx.x;
    int lane = tid & 63, wc = tid >> 6;
    int bm = blockIdx.x * 64;
    f32x4 acc[4][4] = {};
    int grow = lane >> 3;
    int gcol = (((lane & 7) ^ grow) << 3);

    auto stage = [&](int k0, int b) {
        #pragma unroll
        for (int i = 0; i < 2; ++i) {
            int ra = wc * 16 + i * 8;
            GLOAD16(A + (size_t)(bm + ra + grow) * K + k0 + gcol, &As[b][ra * BKT]);
        }
        #pragma unroll
        for (int i = 0; i < 8; ++i) {
            int rb = wc * 64 + i * 8;
            GLOAD16(Bt + (size_t)(rb + grow) * K + k0 + gcol, &Bs[b][rb * BKT]);
        }
    };

    stage(0, 0);
    __syncthreads();
    int KT = K / BKT;
    for (int t = 0; t < KT; ++t) {
        int cur = t & 1;
        if (t + 1 < KT) stage((t + 1) * BKT, cur ^ 1);
        int rlo = lane & 15, khalf = lane >> 4;
        short8 af[4][2], bfr[4][2];
        #pragma unroll
        for (int mi = 0; mi < 4; ++mi) {
            int row = mi * 16 + rlo;
            #pragma unroll
            for (int kk = 0; kk < 2; ++kk) {
                int slot = khalf + kk * 4;
                af[mi][kk] = *(const short8*)(&As[cur][row * BKT + ((slot ^ (row & 7)) << 3)]);
            }
        }
        #pragma unroll
        for (int ni = 0; ni < 4; ++ni) {
            int col = wc * 64 + ni * 16 + rlo;
            #pragma unroll
            for (int kk = 0; kk < 2; ++kk) {
                int slot = khalf + kk * 4;
                bfr[ni][kk] = *(const short8*)(&Bs[cur][col * BKT + ((slot ^ (col & 7)) << 3)]);
            }
        }
        #pragma unroll
        for (int mi = 0; mi < 4; ++mi)
            #pragma unroll
            for (int ni = 0; ni < 4; ++ni)
                #pragma unroll
                for (int kk = 0; kk < 2; ++kk)
                    acc[mi][ni] = __builtin_amdgcn_mfma_f32_16x16x32_bf16(
                        af[mi][kk], bfr[ni][kk], acc[mi][ni], 0, 0, 0);
        __syncthreads();
    }

    float* red = (float*)As;
    int col_l = lane & 15, rgrp = lane >> 4;
    int colc[4]; float bias_c[4], g_c[4], be_c[4];
    #pragma unroll
    for (int ni = 0; ni < 4; ++ni) {
        colc[ni] = wc * 64 + ni * 16 + col_l;
        bias_c[ni] = bias[colc[ni]];
        g_c[ni]  = g[colc[ni]];
        be_c[ni] = beta[colc[ni]];
    }
    #pragma unroll
    for (int mi = 0; mi < 4; ++mi) {
        #pragma unroll
        for (int j = 0; j < 4; ++j) {
            int rl = mi * 16 + rgrp * 4 + j;
            int row = bm + rl;
            float s = 0.f, s2 = 0.f;
            if (row < M) {
                #pragma unroll
                for (int ni = 0; ni < 4; ++ni) {
                    float v = acc[mi][ni][j] + bias_c[ni] + res[(size_t)row * 256 + colc[ni]];
                    acc[mi][ni][j] = v;
                    s += v; s2 += v * v;
                }
            }
            #pragma unroll
            for (int d = 1; d < 16; d <<= 1) { s += __shfl_xor(s, d); s2 += __shfl_xor(s2, d); }
            if (col_l == 0) { red[wc * 64 + rl] = s; red[256 + wc * 64 + rl] = s2; }
        }
    }
    __syncthreads();
    if (tid < 64) {
        float s  = red[tid] + red[64 + tid] + red[128 + tid] + red[192 + tid];
        float s2 = red[256 + tid] + red[320 + tid] + red[384 + tid] + red[448 + tid];
        float mean = s * (1.f / 256.f);
        float var = s2 * (1.f / 256.f) - mean * mean;
        red[512 + tid] = mean;
        red[576 + tid] = rsqrtf(var + 1e-5f);
    }
    __syncthreads();
    #pragma unroll
    for (int mi = 0; mi < 4; ++mi) {
        #pragma unroll
        for (int j = 0; j < 4; ++j) {
            int rl = mi * 16 + rgrp * 4 + j;
            int row = bm + rl;
            if (row >= M) continue;
            float mean = red[512 + rl], rs = red[576 + rl];
            #pragma unroll
            for (int ni = 0; ni < 4; ++ni) {
                float o = g_c[ni] * (acc[mi][ni][j] - mean) * rs + be_c[ni];
                outf[(size_t)row * 256 + colc[ni]] = o;
                if (outb) outb[(size_t)row * 256 + colc[ni]] = f2bf(o);
            }
        }
    }
}

// ---- deformable sampling, phase-split, bf16 value, XOR-permuted LDS ----
__global__ __launch_bounds__(256) void ms_sample(
    const u16* __restrict__ value, const float* __restrict__ oa,
    const float* __restrict__ refp, u16* __restrict__ out)
{
    const int starts[4] = {0, 8464, 10580, 11109};
    const int sizes[4]  = {92, 46, 23, 12};
    int t = threadIdx.x;
    int wv = t >> 6, lane = t & 63;
    int n = blockIdx.x * 4 + wv;

    __shared__ uint4  s_ad[4][128];
    __shared__ float4 s_wt[4][128];

    if (n < N_TOK) {
        const float* oan = oa + (size_t)n * 384;
        unsigned int tokbase = (n >= LEN) ? (unsigned)LEN : 0u;
        #pragma unroll
        for (int rep = 0; rep < 2; ++rep) {
            int q = rep * 64 + lane;          // q = h*16 + pt
            int h = q >> 4, pt = q & 15, l = pt >> 2;
            float logit = oan[256 + q];
            float m = logit;
            #pragma unroll
            for (int d = 1; d < 16; d <<= 1) m = fmaxf(m, __shfl_xor(m, d));
            float e = expf(logit - m);
            float ssum = e;
            #pragma unroll
            for (int d = 1; d < 16; d <<= 1) ssum += __shfl_xor(ssum, d);
            float aw = e / ssum;
            float2 off2 = *(const float2*)(oan + 2 * q);
            float2 ref2 = *(const float2*)(refp + (size_t)n * 8 + l * 2);
            int wl = sizes[l];
            float wf = (float)wl;
            float x = ref2.x * wf - 0.5f + off2.x;
            float y = ref2.y * wf - 0.5f + off2.y;
            float x0f = floorf(x), y0f = floorf(y);
            float fx = x - x0f, fy = y - y0f;
            int x0 = (int)x0f, y0 = (int)y0f;
            int x1 = x0 + 1, y1 = y0 + 1;
            float gx = 1.f - fx, gy = 1.f - fy;
            bool bx0 = (unsigned)x0 < (unsigned)wl, bx1 = (unsigned)x1 < (unsigned)wl;
            bool by0 = (unsigned)y0 < (unsigned)wl, by1 = (unsigned)y1 < (unsigned)wl;
            float w00 = (bx0 && by0) ? gx * gy * aw : 0.f;
            float w10 = (bx1 && by0) ? fx * gy * aw : 0.f;
            float w01 = (bx0 && by1) ? gx * fy * aw : 0.f;
            float w11 = (bx1 && by1) ? fx * fy * aw : 0.f;
            int x0c = min(max(x0, 0), wl - 1), x1c = min(max(x1, 0), wl - 1);
            int y0c = min(max(y0, 0), wl - 1), y1c = min(max(y1, 0), wl - 1);
            unsigned int base = (tokbase + (unsigned)starts[l]) * 256u + (unsigned)(h * 32);
            unsigned int r0 = base + (unsigned)(y0c * wl) * 256u;
            unsigned int r1 = base + (unsigned)(y1c * wl) * 256u;
            int idx = pt * 8 + (h ^ (pt & 7));
            s_ad[wv][idx] = make_uint4(r0 + (unsigned)x0c * 256u, r0 + (unsigned)x1c * 256u,
                                       r1 + (unsigned)x0c * 256u, r1 + (unsigned)x1c * 256u);
            s_wt[wv][idx] = make_float4(w00, w10, w01, w11);
        }
    }
    __syncthreads();
    if (n >= N_TOK) return;

    int h = lane >> 3, dq = lane & 7;
    unsigned int colo = (unsigned)(dq * 4);
    float a0 = 0.f, a1 = 0.f, a2 = 0.f, a3 = 0.f;

    #pragma unroll 8
    for (int pt = 0; pt < 16; ++pt) {
        int idx = pt * 8 + (h ^ (pt & 7));
        uint4 ad = s_ad[wv][idx];
        float4 wt = s_wt[wv][idx];
        uint2 u00 = *(const uint2*)(value + ad.x + colo);
        uint2 u10 = *(const uint2*)(value + ad.y + colo);
        uint2 u01 = *(const uint2*)(value + ad.z + colo);
        uint2 u11 = *(const uint2*)(value + ad.w + colo);
        a0 += wt.x * bflo(u00.x) + wt.y * bflo(u10.x) + wt.z * bflo(u01.x) + wt.w * bflo(u11.x);
        a1 += wt.x * bfhi(u00.x) + wt.y * bfhi(u10.x) + wt.z * bfhi(u01.x) + wt.w * bfhi(u11.x);
        a2 += wt.x * bflo(u00.y) + wt.y * bflo(u10.y) + wt.z * bflo(u01.y) + wt.w * bflo(u11.y);
        a3 += wt.x * bfhi(u00.y) + wt.y * bfhi(u10.y) + wt.z * bfhi(u01.y) + wt.w * bfhi(u11.y);
    }
    u16 o[4] = { f2bf(a0), f2bf(a1), f2bf(a2), f2bf(a3) };
    *(ushort4*)(out + (size_t)n * 256 + h * 32 + dq * 4) = *(ushort4*)o;
}

extern "C" void kernel_launch(void* const* d_in, const int* in_sizes, int n_in,
                              void* d_out, int out_size, void* d_ws, size_t ws_size,
                              hipStream_t stream) {
    const float* src    = (const float*)d_in[0];
    const float* pos    = (const float*)d_in[1];
    const float* refp   = (const float*)d_in[2];
    const float* w_value= (const float*)d_in[3];
    const float* b_value= (const float*)d_in[4];
    const float* w_off  = (const float*)d_in[5];
    const float* b_off  = (const float*)d_in[6];
    const float* w_attn = (const float*)d_in[7];
    const float* b_attn = (const float*)d_in[8];
    const float* w_out  = (const float*)d_in[9];
    const float* b_out  = (const float*)d_in[10];
    const float* ln1_g  = (const float*)d_in[11];
    const float* ln1_b  = (const float*)d_in[12];
    const float* w1     = (const float*)d_in[13];
    const float* b1     = (const float*)d_in[14];
    const float* w2     = (const float*)d_in[15];
    const float* b2     = (const float*)d_in[16];
    const float* ln2_g  = (const float*)d_in[17];
    const float* ln2_b  = (const float*)d_in[18];

    // ws layout (bytes):
    //   Vb  [0,          11523072)  bf16 value        } dead after ms_sample
    //   OA  [11523072,   46092288)  f32 off|attn      }
    //   X   [0,          23046144)  f32 LN1 out   (overlays Vb/OA after death)
    //   Xb  [23046144,   34569216)  bf16 LN1 out  (overlay)
    //   Sb  [46092288,   57615360)  bf16 sampled
    //   Hb  [57615360,  103707648)  bf16 FFN hidden
    //   weights [103707648, 105216512)
    char* w = (char*)d_ws;
    u16*   Vb = (u16*)w;
    float* OA = (float*)(w + 11523072);
    float* X  = (float*)w;
    u16*   Xb = (u16*)(w + 23046144);
    u16*   Sb = (u16*)(w + 46092288);
    u16*   Hb = (u16*)(w + 57615360);
    char*  WB = w + 103707648;
    u16* wv_t   = (u16*)WB;
    u16* woa_t  = wv_t + 65536;
    u16* wout_t = woa_t + 98304;
    u16* w1_t   = wout_t + 65536;
    u16* w2_t   = w1_t + 262144;
    float* boa  = (float*)(w2_t + 262144);
    float* out  = (float*)d_out;

    dim3 blk(256);
    int MB = (N_TOK + BMT - 1) / BMT;  // 176

    wprep<<<dim3(2946), blk, 0, stream>>>(w_value, w_off, w_attn, w_out, w1, w2,
                                          b_off, b_attn, wv_t, woa_t, wout_t, w1_t, w2_t, boa);
    // value(bf16) + [off|attn](f32) in one dispatch
    gemm_qv<<<dim3(5, MB), blk, 0, stream>>>(src, pos, wv_t, woa_t, b_value, boa, Vb, OA);
    // sampling (fused softmax) -> Sb bf16
    ms_sample<<<dim3((N_TOK + 3) / 4), blk, 0, stream>>>(Vb, OA, refp, Sb);
    // x = LN1(src + S @ w_out + b_out) -> X f32, Xb bf16
    gemm_ln<<<dim3((N_TOK + 63) / 64), blk, 0, stream>>>(Sb, wout_t, b_out, src,
                                                         ln1_g, ln1_b, X, Xb, N_TOK, 256);
    // hidden = relu(x @ w1 + b1) -> Hb bf16
    gemm_mfma<<<dim3(8, MB), blk, 0, stream>>>(Xb, w1_t, b1, nullptr, Hb, N_TOK, 1024, 256, 1);
    // out = LN2(x + hidden @ w2 + b2) -> d_out f32
    gemm_ln<<<dim3((N_TOK + 63) / 64), blk, 0, stream>>>(Hb, w2_t, b2, X,
                                                         ln2_g, ln2_b, out, nullptr, N_TOK, 1024);
}